// Round 2
// baseline (1027.017 us; speedup 1.0000x reference)
//
#include <hip/hip_runtime.h>
#include <math.h>

// Problem constants (fixed by reference)
#define B_SZ   4
#define P_SZ   2048
#define H_SZ   16
#define DH_SZ  64
#define DM_SZ  1024
#define M_SZ   (B_SZ * P_SZ)                    // 8192
#define QKV_ELEMS (B_SZ * H_SZ * P_SZ * DH_SZ)  // 8388608 floats per tensor

// ============================================================================
// Fused QKV projection: y = x @ W^T + b for W in {Wq,Wk,Wv}
// x: [M,1024] row-major. W: [1024 out,1024 in] row-major -> A@B^T pattern.
// Output written permuted to [B,H,P,Dh] for the attention kernel.
// 128x128x16 LDS-tiled fp32 GEMM, 256 threads, 8x8 micro-tiles.
// Register-prefetch pipeline: next K-tile's global loads issue before the
// compute block, so ~200-900cy HBM/L2 latency hides under 2048cy of FMA.
// ============================================================================
__global__ __launch_bounds__(256, 2)
void qkv_gemm(const float* __restrict__ x,
              const float* __restrict__ Wq, const float* __restrict__ bq,
              const float* __restrict__ Wk, const float* __restrict__ bk,
              const float* __restrict__ Wv, const float* __restrict__ bv,
              float* __restrict__ q, float* __restrict__ k, float* __restrict__ v)
{
    __shared__ float as[16][132];   // [K][M], pad 132
    __shared__ float bs[16][132];   // [K][N]

    const int bm = blockIdx.x;           // 0..63   (M tiles)
    const int bn = blockIdx.y;           // 0..23   (3*1024/128)
    const int w  = bn >> 3;              // 0=q 1=k 2=v
    const int n0 = (bn & 7) * 128;       // col offset within the weight

    const float* __restrict__ W    = (w == 0) ? Wq : (w == 1) ? Wk : Wv;
    const float* __restrict__ bias = (w == 0) ? bq : (w == 1) ? bk : bv;
    float* __restrict__ out        = (w == 0) ? q  : (w == 1) ? k  : v;

    const int t  = threadIdx.x;
    const int tx = t & 15;
    const int ty = t >> 4;

    const int arow = t >> 2;         // 0..63 (and +64 for second slot)
    const int akc  = (t & 3) << 2;   // 0,4,8,12

    const float* Aptr = x + (size_t)(bm * 128 + arow) * DM_SZ + akc;
    const float* Bptr = W + (size_t)(n0 + arow) * DM_SZ + akc;

    float acc[8][8];
    #pragma unroll
    for (int i = 0; i < 8; ++i)
        #pragma unroll
        for (int j = 0; j < 8; ++j) acc[i][j] = 0.f;

    // prologue: prefetch tile 0
    float4 a0 = *(const float4*)(Aptr);
    float4 a1 = *(const float4*)(Aptr + (size_t)64 * DM_SZ);
    float4 b0 = *(const float4*)(Bptr);
    float4 b1 = *(const float4*)(Bptr + (size_t)64 * DM_SZ);

    for (int k0 = 0; k0 < DM_SZ; k0 += 16) {
        __syncthreads();   // previous iteration's LDS reads complete
        as[akc + 0][arow] = a0.x;  as[akc + 1][arow] = a0.y;
        as[akc + 2][arow] = a0.z;  as[akc + 3][arow] = a0.w;
        as[akc + 0][arow + 64] = a1.x;  as[akc + 1][arow + 64] = a1.y;
        as[akc + 2][arow + 64] = a1.z;  as[akc + 3][arow + 64] = a1.w;
        bs[akc + 0][arow] = b0.x;  bs[akc + 1][arow] = b0.y;
        bs[akc + 2][arow] = b0.z;  bs[akc + 3][arow] = b0.w;
        bs[akc + 0][arow + 64] = b1.x;  bs[akc + 1][arow + 64] = b1.y;
        bs[akc + 2][arow + 64] = b1.z;  bs[akc + 3][arow + 64] = b1.w;
        __syncthreads();
        // prefetch next tile — consumed next iteration, hides under FMAs
        if (k0 + 16 < DM_SZ) {
            const int kn = k0 + 16;
            a0 = *(const float4*)(Aptr + kn);
            a1 = *(const float4*)(Aptr + kn + (size_t)64 * DM_SZ);
            b0 = *(const float4*)(Bptr + kn);
            b1 = *(const float4*)(Bptr + kn + (size_t)64 * DM_SZ);
        }
        #pragma unroll
        for (int kk = 0; kk < 16; ++kk) {
            float af[8], bf[8];
            *(float4*)(af)     = *(const float4*)(&as[kk][ty * 8]);
            *(float4*)(af + 4) = *(const float4*)(&as[kk][ty * 8 + 4]);
            *(float4*)(bf)     = *(const float4*)(&bs[kk][tx * 8]);
            *(float4*)(bf + 4) = *(const float4*)(&bs[kk][tx * 8 + 4]);
            #pragma unroll
            for (int i = 0; i < 8; ++i)
                #pragma unroll
                for (int j = 0; j < 8; ++j)
                    acc[i][j] = fmaf(af[i], bf[j], acc[i][j]);
        }
    }

    // epilogue: add bias, write to [B,H,P,Dh]
    const int gn0 = n0 + tx * 8;      // 0..1023 within this weight
    const int hh  = gn0 >> 6;         // head (8 cols never cross a head: 64%8==0)
    const int d0  = gn0 & 63;
    float bb[8];
    #pragma unroll
    for (int j = 0; j < 8; ++j) bb[j] = bias[gn0 + j];
    #pragma unroll
    for (int i = 0; i < 8; ++i) {
        const int gm = bm * 128 + ty * 8 + i;
        const int b  = gm >> 11;          // /2048
        const int p  = gm & 2047;
        float* o = out + (((size_t)(b * H_SZ + hh)) * P_SZ + p) * DH_SZ + d0;
        const float4 r0 = make_float4(acc[i][0] + bb[0], acc[i][1] + bb[1],
                                      acc[i][2] + bb[2], acc[i][3] + bb[3]);
        const float4 r1 = make_float4(acc[i][4] + bb[4], acc[i][5] + bb[5],
                                      acc[i][6] + bb[6], acc[i][7] + bb[7]);
        *(float4*)(o)     = r0;
        *(float4*)(o + 4) = r1;
    }
}

// ============================================================================
// Banded flash attention.
// time_bias saturates at log(1e-12)=-27.63 for |i-j|>~28; keys at distance
// >64 carry ~1e-12 relative softmax weight (total excluded mass ~3e-7 worst
// case), so softmax over the 3 aligned 64-key chunks covering |i-j|<=64
// matches the full-row reference to ~1e-7 absolute — far below fp32
// accumulation noise. One block per (b,h,qtile64). Online softmax, <=3 chunks.
// ============================================================================
__global__ __launch_bounds__(256, 2)
void attn_banded(const float* __restrict__ qg, const float* __restrict__ kg,
                 const float* __restrict__ vg, const float* __restrict__ pmask,
                 float* __restrict__ ao)
{
    __shared__ float Qs[64][68];
    __shared__ float Ks[64][68];
    __shared__ float Vs[64][68];
    __shared__ float Ps[64][68];
    __shared__ float btab[128];
    __shared__ float mok[64];

    const int bid = blockIdx.x;       // B*H*(P/64) = 2048
    const int qt  = bid & 31;
    const int bh  = bid >> 5;         // b*16+h
    const int b   = bh >> 4;
    const int h   = bh & 15;
    const int q0  = qt * 64;

    const int t   = threadIdx.x;
    const int tx  = t & 15;
    const int ty  = t >> 4;
    const int row = t >> 2;           // 0..63: owned output row
    const int qtr = t & 3;            // quarter of the row / d-quarter

    // stage Q tile [64][64]
    const float* qbase = qg + (size_t)bh * (P_SZ * DH_SZ) + (size_t)q0 * DH_SZ;
    #pragma unroll
    for (int i = 0; i < 4; ++i) {
        const int s = t + 256 * i;
        const int r = s >> 4, c4 = (s & 15) << 2;
        *(float4*)(&Qs[r][c4]) = *(const float4*)(qbase + (size_t)r * DH_SZ + c4);
    }

    float m_run = -1e30f, l_run = 0.f;
    float o_acc[16];
    #pragma unroll
    for (int u = 0; u < 16; ++u) o_acc[u] = 0.f;

    const float* kbase = kg + (size_t)bh * (P_SZ * DH_SZ);
    const float* vbase = vg + (size_t)bh * (P_SZ * DH_SZ);

    for (int ci = -1; ci <= 1; ++ci) {
        const int ct = qt + ci;
        if (ct < 0 || ct >= (P_SZ / 64)) continue;
        const int c0 = ct * 64;

        __syncthreads();   // previous chunk fully consumed (also orders Qs stage)
        #pragma unroll
        for (int i = 0; i < 4; ++i) {
            const int s = t + 256 * i;
            const int r = s >> 4, c4 = (s & 15) << 2;
            *(float4*)(&Ks[r][c4]) = *(const float4*)(kbase + (size_t)(c0 + r) * DH_SZ + c4);
            *(float4*)(&Vs[r][c4]) = *(const float4*)(vbase + (size_t)(c0 + r) * DH_SZ + c4);
        }
        if (t < 64) {
            mok[t] = (pmask[b * P_SZ + c0 + t] > 0.f) ? 0.f : -1e9f;
        } else if (t < 192) {
            const int idx  = t - 64;                 // r-c+64 in [1,127]
            const int diff = (q0 - c0) + idx - 64;
            const float d  = fabsf((float)diff);
            btab[idx] = __logf(__expf(-d) + 1e-12f);
        }
        __syncthreads();

        // S = Q K^T / 8 + bias + mask   (4x4 micro, interleaved cols)
        float accS[4][4];
        #pragma unroll
        for (int i = 0; i < 4; ++i)
            #pragma unroll
            for (int j = 0; j < 4; ++j) accS[i][j] = 0.f;
        #pragma unroll
        for (int d0 = 0; d0 < 64; d0 += 4) {
            float4 qa[4], ka[4];
            #pragma unroll
            for (int i = 0; i < 4; ++i) qa[i] = *(const float4*)(&Qs[ty * 4 + i][d0]);
            #pragma unroll
            for (int j = 0; j < 4; ++j) ka[j] = *(const float4*)(&Ks[tx + 16 * j][d0]);
            #pragma unroll
            for (int i = 0; i < 4; ++i)
                #pragma unroll
                for (int j = 0; j < 4; ++j) {
                    accS[i][j] = fmaf(qa[i].x, ka[j].x, accS[i][j]);
                    accS[i][j] = fmaf(qa[i].y, ka[j].y, accS[i][j]);
                    accS[i][j] = fmaf(qa[i].z, ka[j].z, accS[i][j]);
                    accS[i][j] = fmaf(qa[i].w, ka[j].w, accS[i][j]);
                }
        }
        #pragma unroll
        for (int i = 0; i < 4; ++i)
            #pragma unroll
            for (int j = 0; j < 4; ++j) {
                const int r = ty * 4 + i, c = tx + 16 * j;
                Ps[r][c] = accS[i][j] * 0.125f + btab[r - c + 64] + mok[c];
            }
        __syncthreads();

        // online softmax update for this chunk (4 lanes per row)
        float sv[16];
        float mloc = -1e30f;
        #pragma unroll
        for (int u = 0; u < 16; ++u) {
            sv[u] = Ps[row][qtr * 16 + u];
            mloc  = fmaxf(mloc, sv[u]);
        }
        mloc = fmaxf(mloc, __shfl_xor(mloc, 1));
        mloc = fmaxf(mloc, __shfl_xor(mloc, 2));
        const float mnew  = fmaxf(m_run, mloc);
        const float scale = __expf(m_run - mnew);
        l_run *= scale;
        #pragma unroll
        for (int u = 0; u < 16; ++u) o_acc[u] *= scale;
        float lloc = 0.f;
        #pragma unroll
        for (int u = 0; u < 16; ++u) {
            const float p = __expf(sv[u] - mnew);
            lloc += p;
            Ps[row][qtr * 16 + u] = p;
        }
        lloc += __shfl_xor(lloc, 1);
        lloc += __shfl_xor(lloc, 2);
        l_run += lloc;
        m_run = mnew;
        __syncthreads();

        // O += P @ V  (thread owns row x 16-wide d-quarter)
        const int dd0 = qtr * 16;
        #pragma unroll 4
        for (int c = 0; c < 64; ++c) {
            const float p = Ps[row][c];
            const float* vr = &Vs[c][dd0];
            const float4 v0 = *(const float4*)(vr);
            const float4 v1 = *(const float4*)(vr + 4);
            const float4 v2 = *(const float4*)(vr + 8);
            const float4 v3 = *(const float4*)(vr + 12);
            o_acc[0]  = fmaf(p, v0.x, o_acc[0]);  o_acc[1]  = fmaf(p, v0.y, o_acc[1]);
            o_acc[2]  = fmaf(p, v0.z, o_acc[2]);  o_acc[3]  = fmaf(p, v0.w, o_acc[3]);
            o_acc[4]  = fmaf(p, v1.x, o_acc[4]);  o_acc[5]  = fmaf(p, v1.y, o_acc[5]);
            o_acc[6]  = fmaf(p, v1.z, o_acc[6]);  o_acc[7]  = fmaf(p, v1.w, o_acc[7]);
            o_acc[8]  = fmaf(p, v2.x, o_acc[8]);  o_acc[9]  = fmaf(p, v2.y, o_acc[9]);
            o_acc[10] = fmaf(p, v2.z, o_acc[10]); o_acc[11] = fmaf(p, v2.w, o_acc[11]);
            o_acc[12] = fmaf(p, v3.x, o_acc[12]); o_acc[13] = fmaf(p, v3.y, o_acc[13]);
            o_acc[14] = fmaf(p, v3.z, o_acc[14]); o_acc[15] = fmaf(p, v3.w, o_acc[15]);
        }
    }

    // normalize and write [B,P,H,Dh] (contiguous [B,P,D_MODEL] for O-proj)
    const float inv = 1.0f / l_run;
    const int gp = q0 + row;
    float* obase = ao + (((size_t)(b * P_SZ + gp)) * H_SZ + h) * DH_SZ + qtr * 16;
    *(float4*)(obase)      = make_float4(o_acc[0] * inv,  o_acc[1] * inv,  o_acc[2] * inv,  o_acc[3] * inv);
    *(float4*)(obase + 4)  = make_float4(o_acc[4] * inv,  o_acc[5] * inv,  o_acc[6] * inv,  o_acc[7] * inv);
    *(float4*)(obase + 8)  = make_float4(o_acc[8] * inv,  o_acc[9] * inv,  o_acc[10] * inv, o_acc[11] * inv);
    *(float4*)(obase + 12) = make_float4(o_acc[12] * inv, o_acc[13] * inv, o_acc[14] * inv, o_acc[15] * inv);
}

// ============================================================================
// Output projection: out = (ao @ Wo^T + bo) * patch_mask
// Same register-prefetch pipeline as qkv_gemm.
// ============================================================================
__global__ __launch_bounds__(256, 2)
void o_gemm(const float* __restrict__ ao, const float* __restrict__ Wo,
            const float* __restrict__ bo, const float* __restrict__ pmask,
            float* __restrict__ outp)
{
    __shared__ float as[16][132];
    __shared__ float bs[16][132];

    const int bm = blockIdx.x;       // 0..63
    const int bn = blockIdx.y;       // 0..7
    const int n0 = bn * 128;

    const int t  = threadIdx.x;
    const int tx = t & 15;
    const int ty = t >> 4;
    const int arow = t >> 2;
    const int akc  = (t & 3) << 2;

    const float* Aptr = ao + (size_t)(bm * 128 + arow) * DM_SZ + akc;
    const float* Bptr = Wo + (size_t)(n0 + arow) * DM_SZ + akc;

    float acc[8][8];
    #pragma unroll
    for (int i = 0; i < 8; ++i)
        #pragma unroll
        for (int j = 0; j < 8; ++j) acc[i][j] = 0.f;

    float4 a0 = *(const float4*)(Aptr);
    float4 a1 = *(const float4*)(Aptr + (size_t)64 * DM_SZ);
    float4 b0 = *(const float4*)(Bptr);
    float4 b1 = *(const float4*)(Bptr + (size_t)64 * DM_SZ);

    for (int k0 = 0; k0 < DM_SZ; k0 += 16) {
        __syncthreads();
        as[akc + 0][arow] = a0.x;  as[akc + 1][arow] = a0.y;
        as[akc + 2][arow] = a0.z;  as[akc + 3][arow] = a0.w;
        as[akc + 0][arow + 64] = a1.x;  as[akc + 1][arow + 64] = a1.y;
        as[akc + 2][arow + 64] = a1.z;  as[akc + 3][arow + 64] = a1.w;
        bs[akc + 0][arow] = b0.x;  bs[akc + 1][arow] = b0.y;
        bs[akc + 2][arow] = b0.z;  bs[akc + 3][arow] = b0.w;
        bs[akc + 0][arow + 64] = b1.x;  bs[akc + 1][arow + 64] = b1.y;
        bs[akc + 2][arow + 64] = b1.z;  bs[akc + 3][arow + 64] = b1.w;
        __syncthreads();
        if (k0 + 16 < DM_SZ) {
            const int kn = k0 + 16;
            a0 = *(const float4*)(Aptr + kn);
            a1 = *(const float4*)(Aptr + kn + (size_t)64 * DM_SZ);
            b0 = *(const float4*)(Bptr + kn);
            b1 = *(const float4*)(Bptr + kn + (size_t)64 * DM_SZ);
        }
        #pragma unroll
        for (int kk = 0; kk < 16; ++kk) {
            float af[8], bf[8];
            *(float4*)(af)     = *(const float4*)(&as[kk][ty * 8]);
            *(float4*)(af + 4) = *(const float4*)(&as[kk][ty * 8 + 4]);
            *(float4*)(bf)     = *(const float4*)(&bs[kk][tx * 8]);
            *(float4*)(bf + 4) = *(const float4*)(&bs[kk][tx * 8 + 4]);
            #pragma unroll
            for (int i = 0; i < 8; ++i)
                #pragma unroll
                for (int j = 0; j < 8; ++j)
                    acc[i][j] = fmaf(af[i], bf[j], acc[i][j]);
        }
    }

    const int gn0 = n0 + tx * 8;
    float bb[8];
    #pragma unroll
    for (int j = 0; j < 8; ++j) bb[j] = bo[gn0 + j];
    #pragma unroll
    for (int i = 0; i < 8; ++i) {
        const int gm = bm * 128 + ty * 8 + i;
        const float pm = pmask[gm];
        float* o = outp + (size_t)gm * DM_SZ + gn0;
        const float4 r0 = make_float4((acc[i][0] + bb[0]) * pm, (acc[i][1] + bb[1]) * pm,
                                      (acc[i][2] + bb[2]) * pm, (acc[i][3] + bb[3]) * pm);
        const float4 r1 = make_float4((acc[i][4] + bb[4]) * pm, (acc[i][5] + bb[5]) * pm,
                                      (acc[i][6] + bb[6]) * pm, (acc[i][7] + bb[7]) * pm);
        *(float4*)(o)     = r0;
        *(float4*)(o + 4) = r1;
    }
}

// ============================================================================
extern "C" void kernel_launch(void* const* d_in, const int* in_sizes, int n_in,
                              void* d_out, int out_size, void* d_ws, size_t ws_size,
                              hipStream_t stream)
{
    const float* x     = (const float*)d_in[0];
    const float* pmask = (const float*)d_in[1];
    const float* Wq    = (const float*)d_in[2];
    const float* bq    = (const float*)d_in[3];
    const float* Wk    = (const float*)d_in[4];
    const float* bk    = (const float*)d_in[5];
    const float* Wv    = (const float*)d_in[6];
    const float* bv    = (const float*)d_in[7];
    const float* Wo    = (const float*)d_in[8];
    const float* bo    = (const float*)d_in[9];

    float* ws = (float*)d_ws;
    float* q  = ws;                       // [B,H,P,Dh] 33.5 MB
    float* k  = ws + (size_t)QKV_ELEMS;   // 33.5 MB
    float* v  = ws + (size_t)2 * QKV_ELEMS;
    float* ao = ws + (size_t)3 * QKV_ELEMS;  // [B,P,D] 33.5 MB; total 134 MB

    qkv_gemm<<<dim3(64, 24), 256, 0, stream>>>(x, Wq, bq, Wk, bk, Wv, bv, q, k, v);
    attn_banded<<<dim3(2048), 256, 0, stream>>>(q, k, v, pmask, ao);
    o_gemm<<<dim3(64, 8), 256, 0, stream>>>(ao, Wo, bo, pmask, (float*)d_out);
}

// Round 5
// 428.083 us; speedup vs baseline: 2.3991x; 2.3991x over previous
//
#include <hip/hip_runtime.h>
#include <math.h>

typedef unsigned short u16;
typedef unsigned int   u32;
typedef __attribute__((ext_vector_type(8))) __bf16 bf16x8;  // 4 VGPRs, MFMA A/B frag
typedef __attribute__((ext_vector_type(4))) float  f32x4;   // MFMA C/D frag

// Problem constants (fixed by reference)
#define B_SZ   4
#define P_SZ   2048
#define H_SZ   16
#define DH_SZ  64
#define DM_SZ  1024
#define M_SZ   (B_SZ * P_SZ)                    // 8192
#define QKV_ELEMS (B_SZ * H_SZ * P_SZ * DH_SZ)  // 8388608

// ---------------------------------------------------------------------------
// bf16 helpers (RNE; inputs are finite, no NaN handling needed)
// ---------------------------------------------------------------------------
__device__ __forceinline__ u16 f2bf(float f) {
    u32 u = __float_as_uint(f);
    u += 0x7fffu + ((u >> 16) & 1u);
    return (u16)(u >> 16);
}
__device__ __forceinline__ float bf2f(u16 h) {
    return __uint_as_float(((u32)h) << 16);
}
// async global->LDS, 16B per lane; LDS dst is wave-uniform (HW adds lane*16B)
__device__ __forceinline__ void gload16(const u16* g, u16* l) {
    __builtin_amdgcn_global_load_lds((const __attribute__((address_space(1))) void*)g,
                                     (__attribute__((address_space(3))) void*)l,
                                     16, 0, 0);
}

// ---------------------------------------------------------------------------
// Split fp32 -> (hi, lo) bf16 pairs for x and the 4 weight matrices.
// ---------------------------------------------------------------------------
__global__ __launch_bounds__(256)
void split_inputs(const float4* __restrict__ x4,
                  const float4* __restrict__ wq4, const float4* __restrict__ wk4,
                  const float4* __restrict__ wv4, const float4* __restrict__ wo4,
                  u16* __restrict__ xh, u16* __restrict__ xl,
                  u16* __restrict__ qh, u16* __restrict__ ql,
                  u16* __restrict__ kh, u16* __restrict__ kl,
                  u16* __restrict__ vh, u16* __restrict__ vl,
                  u16* __restrict__ oh, u16* __restrict__ ol)
{
    const int total4 = 3145728;     // (8388608 + 4*1048576)/4
    for (int i = blockIdx.x * blockDim.x + threadIdx.x; i < total4;
         i += gridDim.x * blockDim.x) {
        const float4* src; u16 *dh, *dl; int off;
        if (i < 2097152) { src = x4; dh = xh; dl = xl; off = i; }
        else {
            const int j = i - 2097152;
            const int r = j >> 18;            // which W (262144 float4 each)
            off = j & 262143;
            switch (r) {
                case 0:  src = wq4; dh = qh; dl = ql; break;
                case 1:  src = wk4; dh = kh; dl = kl; break;
                case 2:  src = wv4; dh = vh; dl = vl; break;
                default: src = wo4; dh = oh; dl = ol; break;
            }
        }
        const float4 f = src[off];
        const u16 h0 = f2bf(f.x), h1 = f2bf(f.y), h2 = f2bf(f.z), h3 = f2bf(f.w);
        const u16 l0 = f2bf(f.x - bf2f(h0)), l1 = f2bf(f.y - bf2f(h1));
        const u16 l2 = f2bf(f.z - bf2f(h2)), l3 = f2bf(f.w - bf2f(h3));
        uint2 H, L;
        H.x = (u32)h0 | ((u32)h1 << 16);  H.y = (u32)h2 | ((u32)h3 << 16);
        L.x = (u32)l0 | ((u32)l1 << 16);  L.y = (u32)l2 | ((u32)l3 << 16);
        *(uint2*)(dh + (size_t)off * 4) = H;
        *(uint2*)(dl + (size_t)off * 4) = L;
    }
}

// ---------------------------------------------------------------------------
// Split-bf16 MFMA GEMM: C = A @ B^T in ~fp32 precision via
//   Ahi@Bhi + Ahi@Blo + Alo@Bhi   (fp32 MFMA accumulate; lo*lo ~2^-18, dropped)
// m97 structure: 128x128 tile, BK=32, 4 waves (2x2 of 64x64), 2-barrier K-loop,
// global_load_lds width 16. mfma_f32_16x16x32_bf16:
//   A frag: row=lane&15, k=(lane>>4)*8+j (8 contig bf16)   [m92 pattern]
//   C/D:    col=lane&15, row=(lane>>4)*4+reg               [m89 verified]
// QKV flavor: blockIdx.z selects W; epilogue writes permuted [B,H,P,Dh] + bias.
// ---------------------------------------------------------------------------
__global__ __launch_bounds__(256, 2)
void qkv_mfma(const u16* __restrict__ xh, const u16* __restrict__ xl,
              const u16* __restrict__ Wqh, const u16* __restrict__ Wql,
              const u16* __restrict__ Wkh, const u16* __restrict__ Wkl,
              const u16* __restrict__ Wvh, const u16* __restrict__ Wvl,
              const float* __restrict__ bq, const float* __restrict__ bk,
              const float* __restrict__ bv,
              float* __restrict__ qo, float* __restrict__ ko, float* __restrict__ vo)
{
    __shared__ u16 Ah[4096], Al[4096], Bh[4096], Bl[4096];   // 4 x [128][32] bf16

    const int bm = blockIdx.x;           // M tile (64)
    const int n0 = blockIdx.y * 128;     // N tile within weight (8)
    const int z  = blockIdx.z;           // 0=q 1=k 2=v
    const u16*  Wh   = (z == 0) ? Wqh : (z == 1) ? Wkh : Wvh;
    const u16*  Wl   = (z == 0) ? Wql : (z == 1) ? Wkl : Wvl;
    const float* bias = (z == 0) ? bq : (z == 1) ? bk : bv;
    float* out        = (z == 0) ? qo : (z == 1) ? ko : vo;

    const int t = threadIdx.x, w = t >> 6, lane = t & 63;
    const int lr = lane >> 2, lk = lane & 3;          // staging: row-in-chunk, k-slot
    const int wr = w >> 1, wc = w & 1;                // wave grid 2x2
    const int fr = lane & 15, fq = lane >> 4;         // frag row/col, k-group

    // wave w stages rows [w*32, w*32+32) of each 128x32 LDS tile
    const u16* aSh = xh + (size_t)(bm * 128 + w * 32 + lr) * DM_SZ + lk * 8;
    const u16* aSl = xl + (size_t)(bm * 128 + w * 32 + lr) * DM_SZ + lk * 8;
    const u16* bSh = Wh + (size_t)(n0 + w * 32 + lr) * DM_SZ + lk * 8;
    const u16* bSl = Wl + (size_t)(n0 + w * 32 + lr) * DM_SZ + lk * 8;
    u16* dAh = &Ah[w * 1024]; u16* dAl = &Al[w * 1024];
    u16* dBh = &Bh[w * 1024]; u16* dBl = &Bl[w * 1024];

    const int aoff = (wr * 64 + fr) * 32 + fq * 8;    // + fm*512
    const int boff = (wc * 64 + fr) * 32 + fq * 8;    // + fn*512

    f32x4 acc[4][4];
    #pragma unroll
    for (int i = 0; i < 4; ++i)
        #pragma unroll
        for (int j = 0; j < 4; ++j) acc[i][j] = (f32x4)0.f;

    for (int kt = 0; kt < DM_SZ / 32; ++kt) {
        const int ko_ = kt * 32;
        __syncthreads();                 // prev iter's LDS reads done
        gload16(aSh + ko_, dAh); gload16(aSh + ko_ + 16 * DM_SZ, dAh + 512);
        gload16(aSl + ko_, dAl); gload16(aSl + ko_ + 16 * DM_SZ, dAl + 512);
        gload16(bSh + ko_, dBh); gload16(bSh + ko_ + 16 * DM_SZ, dBh + 512);
        gload16(bSl + ko_, dBl); gload16(bSl + ko_ + 16 * DM_SZ, dBl + 512);
        __syncthreads();                 // compiler drains vmcnt(0) before barrier

        bf16x8 fah[4], fal[4], fbh[4], fbl[4];
        #pragma unroll
        for (int f = 0; f < 4; ++f) {
            fah[f] = *(const bf16x8*)&Ah[aoff + f * 512];
            fal[f] = *(const bf16x8*)&Al[aoff + f * 512];
            fbh[f] = *(const bf16x8*)&Bh[boff + f * 512];
            fbl[f] = *(const bf16x8*)&Bl[boff + f * 512];
        }
        #pragma unroll
        for (int i = 0; i < 4; ++i)
            #pragma unroll
            for (int j = 0; j < 4; ++j) {
                acc[i][j] = __builtin_amdgcn_mfma_f32_16x16x32_bf16(fah[i], fbh[j], acc[i][j], 0, 0, 0);
                acc[i][j] = __builtin_amdgcn_mfma_f32_16x16x32_bf16(fah[i], fbl[j], acc[i][j], 0, 0, 0);
                acc[i][j] = __builtin_amdgcn_mfma_f32_16x16x32_bf16(fal[i], fbh[j], acc[i][j], 0, 0, 0);
            }
    }

    // epilogue: bias add, write permuted [B,H,P,Dh]
    #pragma unroll
    for (int i = 0; i < 4; ++i) {
        const int rbase = bm * 128 + wr * 64 + i * 16 + fq * 4;
        #pragma unroll
        for (int j = 0; j < 4; ++j) {
            const int n  = n0 + wc * 64 + j * 16 + fr;
            const float bb = bias[n];
            const int hh = n >> 6, dd = n & 63;     // 16-col frags never cross heads
            #pragma unroll
            for (int r = 0; r < 4; ++r) {
                const int m = rbase + r;
                const int b = m >> 11, p = m & 2047;
                out[(((size_t)(b * H_SZ + hh)) * P_SZ + p) * DH_SZ + dd] = acc[i][j][r] + bb;
            }
        }
    }
}

// ---------------------------------------------------------------------------
// O-projection flavor: out = (ao @ Wo^T + bo) * patch_mask, plain [M,1024].
// ---------------------------------------------------------------------------
__global__ __launch_bounds__(256, 2)
void o_mfma(const u16* __restrict__ aoh, const u16* __restrict__ aol,
            const u16* __restrict__ Woh, const u16* __restrict__ Wol,
            const float* __restrict__ bo, const float* __restrict__ pmask,
            float* __restrict__ outp)
{
    __shared__ u16 Ah[4096], Al[4096], Bh[4096], Bl[4096];

    const int bm = blockIdx.x;
    const int n0 = blockIdx.y * 128;
    const int t = threadIdx.x, w = t >> 6, lane = t & 63;
    const int lr = lane >> 2, lk = lane & 3;
    const int wr = w >> 1, wc = w & 1;
    const int fr = lane & 15, fq = lane >> 4;

    const u16* aSh = aoh + (size_t)(bm * 128 + w * 32 + lr) * DM_SZ + lk * 8;
    const u16* aSl = aol + (size_t)(bm * 128 + w * 32 + lr) * DM_SZ + lk * 8;
    const u16* bSh = Woh + (size_t)(n0 + w * 32 + lr) * DM_SZ + lk * 8;
    const u16* bSl = Wol + (size_t)(n0 + w * 32 + lr) * DM_SZ + lk * 8;
    u16* dAh = &Ah[w * 1024]; u16* dAl = &Al[w * 1024];
    u16* dBh = &Bh[w * 1024]; u16* dBl = &Bl[w * 1024];

    const int aoff = (wr * 64 + fr) * 32 + fq * 8;
    const int boff = (wc * 64 + fr) * 32 + fq * 8;

    f32x4 acc[4][4];
    #pragma unroll
    for (int i = 0; i < 4; ++i)
        #pragma unroll
        for (int j = 0; j < 4; ++j) acc[i][j] = (f32x4)0.f;

    for (int kt = 0; kt < DM_SZ / 32; ++kt) {
        const int ko_ = kt * 32;
        __syncthreads();
        gload16(aSh + ko_, dAh); gload16(aSh + ko_ + 16 * DM_SZ, dAh + 512);
        gload16(aSl + ko_, dAl); gload16(aSl + ko_ + 16 * DM_SZ, dAl + 512);
        gload16(bSh + ko_, dBh); gload16(bSh + ko_ + 16 * DM_SZ, dBh + 512);
        gload16(bSl + ko_, dBl); gload16(bSl + ko_ + 16 * DM_SZ, dBl + 512);
        __syncthreads();

        bf16x8 fah[4], fal[4], fbh[4], fbl[4];
        #pragma unroll
        for (int f = 0; f < 4; ++f) {
            fah[f] = *(const bf16x8*)&Ah[aoff + f * 512];
            fal[f] = *(const bf16x8*)&Al[aoff + f * 512];
            fbh[f] = *(const bf16x8*)&Bh[boff + f * 512];
            fbl[f] = *(const bf16x8*)&Bl[boff + f * 512];
        }
        #pragma unroll
        for (int i = 0; i < 4; ++i)
            #pragma unroll
            for (int j = 0; j < 4; ++j) {
                acc[i][j] = __builtin_amdgcn_mfma_f32_16x16x32_bf16(fah[i], fbh[j], acc[i][j], 0, 0, 0);
                acc[i][j] = __builtin_amdgcn_mfma_f32_16x16x32_bf16(fah[i], fbl[j], acc[i][j], 0, 0, 0);
                acc[i][j] = __builtin_amdgcn_mfma_f32_16x16x32_bf16(fal[i], fbh[j], acc[i][j], 0, 0, 0);
            }
    }

    #pragma unroll
    for (int i = 0; i < 4; ++i) {
        const int rbase = bm * 128 + wr * 64 + i * 16 + fq * 4;
        #pragma unroll
        for (int j = 0; j < 4; ++j) {
            const int n  = n0 + wc * 64 + j * 16 + fr;
            const float bb = bo[n];
            #pragma unroll
            for (int r = 0; r < 4; ++r) {
                const int m = rbase + r;
                outp[(size_t)m * DM_SZ + n] = (acc[i][j][r] + bb) * pmask[m];
            }
        }
    }
}

// ---------------------------------------------------------------------------
// Banded flash attention (fp32 math, identical to the run that passed at
// absmax 0.0078). time_bias saturates at log(1e-12)=-27.63 for |i-j|>~28;
// keys beyond the 3 aligned 64-key chunks carry ~1e-12 relative weight.
// Epilogue emits hi/lo bf16 directly for the split-bf16 O-projection.
// ---------------------------------------------------------------------------
__global__ __launch_bounds__(256, 2)
void attn_banded(const float* __restrict__ qg, const float* __restrict__ kg,
                 const float* __restrict__ vg, const float* __restrict__ pmask,
                 u16* __restrict__ aoh, u16* __restrict__ aol)
{
    __shared__ float Qs[64][68];
    __shared__ float Ks[64][68];
    __shared__ float Vs[64][68];
    __shared__ float Ps[64][68];
    __shared__ float btab[128];
    __shared__ float mok[64];

    const int bid = blockIdx.x;       // B*H*(P/64) = 2048
    const int qt  = bid & 31;
    const int bh  = bid >> 5;
    const int b   = bh >> 4;
    const int h   = bh & 15;
    const int q0  = qt * 64;

    const int t   = threadIdx.x;
    const int tx  = t & 15;
    const int ty  = t >> 4;
    const int row = t >> 2;
    const int qtr = t & 3;

    const float* qbase = qg + (size_t)bh * (P_SZ * DH_SZ) + (size_t)q0 * DH_SZ;
    #pragma unroll
    for (int i = 0; i < 4; ++i) {
        const int s = t + 256 * i;
        const int r = s >> 4, c4 = (s & 15) << 2;
        *(float4*)(&Qs[r][c4]) = *(const float4*)(qbase + (size_t)r * DH_SZ + c4);
    }

    float m_run = -1e30f, l_run = 0.f;
    float o_acc[16];
    #pragma unroll
    for (int u = 0; u < 16; ++u) o_acc[u] = 0.f;

    const float* kbase = kg + (size_t)bh * (P_SZ * DH_SZ);
    const float* vbase = vg + (size_t)bh * (P_SZ * DH_SZ);

    for (int ci = -1; ci <= 1; ++ci) {
        const int ct = qt + ci;
        if (ct < 0 || ct >= (P_SZ / 64)) continue;
        const int c0 = ct * 64;

        __syncthreads();
        #pragma unroll
        for (int i = 0; i < 4; ++i) {
            const int s = t + 256 * i;
            const int r = s >> 4, c4 = (s & 15) << 2;
            *(float4*)(&Ks[r][c4]) = *(const float4*)(kbase + (size_t)(c0 + r) * DH_SZ + c4);
            *(float4*)(&Vs[r][c4]) = *(const float4*)(vbase + (size_t)(c0 + r) * DH_SZ + c4);
        }
        if (t < 64) {
            mok[t] = (pmask[b * P_SZ + c0 + t] > 0.f) ? 0.f : -1e9f;
        } else if (t < 192) {
            const int idx  = t - 64;
            const int diff = (q0 - c0) + idx - 64;
            const float d  = fabsf((float)diff);
            btab[idx] = __logf(__expf(-d) + 1e-12f);
        }
        __syncthreads();

        float accS[4][4];
        #pragma unroll
        for (int i = 0; i < 4; ++i)
            #pragma unroll
            for (int j = 0; j < 4; ++j) accS[i][j] = 0.f;
        #pragma unroll
        for (int d0 = 0; d0 < 64; d0 += 4) {
            float4 qa[4], ka[4];
            #pragma unroll
            for (int i = 0; i < 4; ++i) qa[i] = *(const float4*)(&Qs[ty * 4 + i][d0]);
            #pragma unroll
            for (int j = 0; j < 4; ++j) ka[j] = *(const float4*)(&Ks[tx + 16 * j][d0]);
            #pragma unroll
            for (int i = 0; i < 4; ++i)
                #pragma unroll
                for (int j = 0; j < 4; ++j) {
                    accS[i][j] = fmaf(qa[i].x, ka[j].x, accS[i][j]);
                    accS[i][j] = fmaf(qa[i].y, ka[j].y, accS[i][j]);
                    accS[i][j] = fmaf(qa[i].z, ka[j].z, accS[i][j]);
                    accS[i][j] = fmaf(qa[i].w, ka[j].w, accS[i][j]);
                }
        }
        #pragma unroll
        for (int i = 0; i < 4; ++i)
            #pragma unroll
            for (int j = 0; j < 4; ++j) {
                const int r = ty * 4 + i, c = tx + 16 * j;
                Ps[r][c] = accS[i][j] * 0.125f + btab[r - c + 64] + mok[c];
            }
        __syncthreads();

        float sv[16];
        float mloc = -1e30f;
        #pragma unroll
        for (int u = 0; u < 16; ++u) {
            sv[u] = Ps[row][qtr * 16 + u];
            mloc  = fmaxf(mloc, sv[u]);
        }
        mloc = fmaxf(mloc, __shfl_xor(mloc, 1));
        mloc = fmaxf(mloc, __shfl_xor(mloc, 2));
        const float mnew  = fmaxf(m_run, mloc);
        const float scale = __expf(m_run - mnew);
        l_run *= scale;
        #pragma unroll
        for (int u = 0; u < 16; ++u) o_acc[u] *= scale;
        float lloc = 0.f;
        #pragma unroll
        for (int u = 0; u < 16; ++u) {
            const float p = __expf(sv[u] - mnew);
            lloc += p;
            Ps[row][qtr * 16 + u] = p;
        }
        lloc += __shfl_xor(lloc, 1);
        lloc += __shfl_xor(lloc, 2);
        l_run += lloc;
        m_run = mnew;
        __syncthreads();

        const int dd0 = qtr * 16;
        #pragma unroll 4
        for (int c = 0; c < 64; ++c) {
            const float p = Ps[row][c];
            const float* vr = &Vs[c][dd0];
            const float4 v0 = *(const float4*)(vr);
            const float4 v1 = *(const float4*)(vr + 4);
            const float4 v2 = *(const float4*)(vr + 8);
            const float4 v3 = *(const float4*)(vr + 12);
            o_acc[0]  = fmaf(p, v0.x, o_acc[0]);  o_acc[1]  = fmaf(p, v0.y, o_acc[1]);
            o_acc[2]  = fmaf(p, v0.z, o_acc[2]);  o_acc[3]  = fmaf(p, v0.w, o_acc[3]);
            o_acc[4]  = fmaf(p, v1.x, o_acc[4]);  o_acc[5]  = fmaf(p, v1.y, o_acc[5]);
            o_acc[6]  = fmaf(p, v1.z, o_acc[6]);  o_acc[7]  = fmaf(p, v1.w, o_acc[7]);
            o_acc[8]  = fmaf(p, v2.x, o_acc[8]);  o_acc[9]  = fmaf(p, v2.y, o_acc[9]);
            o_acc[10] = fmaf(p, v2.z, o_acc[10]); o_acc[11] = fmaf(p, v2.w, o_acc[11]);
            o_acc[12] = fmaf(p, v3.x, o_acc[12]); o_acc[13] = fmaf(p, v3.y, o_acc[13]);
            o_acc[14] = fmaf(p, v3.z, o_acc[14]); o_acc[15] = fmaf(p, v3.w, o_acc[15]);
        }
    }

    // normalize; emit hi/lo bf16 into [B,P,H,Dh] (row-major [M,1024]) for o_mfma
    const float inv = 1.0f / l_run;
    const int gp = q0 + row;
    const size_t idx = ((size_t)(b * P_SZ + gp)) * DM_SZ + h * DH_SZ + qtr * 16;
    u32 Hp[8], Lp[8];
    #pragma unroll
    for (int u2 = 0; u2 < 8; ++u2) {
        const float v0 = o_acc[2 * u2] * inv, v1 = o_acc[2 * u2 + 1] * inv;
        const u16 h0 = f2bf(v0), h1 = f2bf(v1);
        const u16 l0 = f2bf(v0 - bf2f(h0)), l1 = f2bf(v1 - bf2f(h1));
        Hp[u2] = (u32)h0 | ((u32)h1 << 16);
        Lp[u2] = (u32)l0 | ((u32)l1 << 16);
    }
    uint4 a, c;
    a.x = Hp[0]; a.y = Hp[1]; a.z = Hp[2]; a.w = Hp[3];
    c.x = Hp[4]; c.y = Hp[5]; c.z = Hp[6]; c.w = Hp[7];
    *(uint4*)(aoh + idx)     = a;
    *(uint4*)(aoh + idx + 8) = c;
    a.x = Lp[0]; a.y = Lp[1]; a.z = Lp[2]; a.w = Lp[3];
    c.x = Lp[4]; c.y = Lp[5]; c.z = Lp[6]; c.w = Lp[7];
    *(uint4*)(aol + idx)     = a;
    *(uint4*)(aol + idx + 8) = c;
}

// ===========================================================================
extern "C" void kernel_launch(void* const* d_in, const int* in_sizes, int n_in,
                              void* d_out, int out_size, void* d_ws, size_t ws_size,
                              hipStream_t stream)
{
    const float* x     = (const float*)d_in[0];
    const float* pmask = (const float*)d_in[1];
    const float* Wq    = (const float*)d_in[2];
    const float* bq    = (const float*)d_in[3];
    const float* Wk    = (const float*)d_in[4];
    const float* bk    = (const float*)d_in[5];
    const float* Wv    = (const float*)d_in[6];
    const float* bv    = (const float*)d_in[7];
    const float* Wo    = (const float*)d_in[8];
    const float* bo    = (const float*)d_in[9];

    // workspace layout — 112 MiB (< 128 MiB bound proven by the fp32 run):
    //  xh,xl        2 x 8388608 u16 = 32 MiB  (reused as aoh/aol after qkv_mfma)
    //  8 x W hi/lo  8 x 1048576 u16 = 16 MiB
    //  q fp32       8388608 f32     = 32 MiB
    //  k fp32       8388608 f32     = 32 MiB
    // V (fp32, 32 MiB) lives in d_out: written by qkv_mfma, read by attn,
    // then o_mfma fully overwrites d_out with the final output (stream order).
    u16* xh  = (u16*)d_ws;
    u16* xl  = xh + (size_t)QKV_ELEMS;
    u16* wqh = xl + (size_t)QKV_ELEMS;
    u16* wql = wqh + 1048576;
    u16* wkh = wql + 1048576;
    u16* wkl = wkh + 1048576;
    u16* wvh = wkl + 1048576;
    u16* wvl = wvh + 1048576;
    u16* woh = wvl + 1048576;
    u16* wol = woh + 1048576;
    float* q = (float*)(wol + 1048576);
    float* k = q + (size_t)QKV_ELEMS;
    float* v = (float*)d_out;          // scratch until o_mfma overwrites
    u16* aoh = xh;   // x splits dead after qkv_mfma; stream order makes this safe
    u16* aol = xl;

    split_inputs<<<dim3(1024), 256, 0, stream>>>(
        (const float4*)x, (const float4*)Wq, (const float4*)Wk,
        (const float4*)Wv, (const float4*)Wo,
        xh, xl, wqh, wql, wkh, wkl, wvh, wvl, woh, wol);

    qkv_mfma<<<dim3(64, 8, 3), 256, 0, stream>>>(
        xh, xl, wqh, wql, wkh, wkl, wvh, wvl, bq, bk, bv, q, k, v);

    attn_banded<<<dim3(2048), 256, 0, stream>>>(q, k, v, pmask, aoh, aol);

    o_mfma<<<dim3(64, 8), 256, 0, stream>>>(aoh, aol, woh, wol, bo, pmask, (float*)d_out);
}

// Round 9
// 385.449 us; speedup vs baseline: 2.6645x; 1.1106x over previous
//
#include <hip/hip_runtime.h>
#include <math.h>

typedef unsigned short u16;
typedef unsigned int   u32;
typedef __attribute__((ext_vector_type(8))) __bf16 bf16x8;  // 4 VGPRs, MFMA A/B frag
typedef __attribute__((ext_vector_type(4))) float  f32x4;   // MFMA C/D frag

#define B_SZ   4
#define P_SZ   2048
#define H_SZ   16
#define DH_SZ  64
#define DM_SZ  1024
#define M_SZ   (B_SZ * P_SZ)                    // 8192
#define QKV_ELEMS (B_SZ * H_SZ * P_SZ * DH_SZ)  // 8388608

// ---------------------------------------------------------------------------
__device__ __forceinline__ u16 f2bf(float f) {
    u32 u = __float_as_uint(f);
    u += 0x7fffu + ((u >> 16) & 1u);
    return (u16)(u >> 16);
}
__device__ __forceinline__ float bf2f(u16 h) {
    return __uint_as_float(((u32)h) << 16);
}
__device__ __forceinline__ void gload16(const u16* g, u16* l) {
    __builtin_amdgcn_global_load_lds((const __attribute__((address_space(1))) void*)g,
                                     (__attribute__((address_space(3))) void*)l,
                                     16, 0, 0);
}

// ---------------------------------------------------------------------------
// Split fp32 -> (hi, lo) bf16 pairs for x and the 4 weight matrices.
// ---------------------------------------------------------------------------
__global__ __launch_bounds__(256)
void split_inputs(const float4* __restrict__ x4,
                  const float4* __restrict__ wq4, const float4* __restrict__ wk4,
                  const float4* __restrict__ wv4, const float4* __restrict__ wo4,
                  u16* __restrict__ xh, u16* __restrict__ xl,
                  u16* __restrict__ qh, u16* __restrict__ ql,
                  u16* __restrict__ kh, u16* __restrict__ kl,
                  u16* __restrict__ vh, u16* __restrict__ vl,
                  u16* __restrict__ oh, u16* __restrict__ ol)
{
    const int total4 = 3145728;
    for (int i = blockIdx.x * blockDim.x + threadIdx.x; i < total4;
         i += gridDim.x * blockDim.x) {
        const float4* src; u16 *dh, *dl; int off;
        if (i < 2097152) { src = x4; dh = xh; dl = xl; off = i; }
        else {
            const int j = i - 2097152;
            const int r = j >> 18;
            off = j & 262143;
            switch (r) {
                case 0:  src = wq4; dh = qh; dl = ql; break;
                case 1:  src = wk4; dh = kh; dl = kl; break;
                case 2:  src = wv4; dh = vh; dl = vl; break;
                default: src = wo4; dh = oh; dl = ol; break;
            }
        }
        const float4 f = src[off];
        const u16 h0 = f2bf(f.x), h1 = f2bf(f.y), h2 = f2bf(f.z), h3 = f2bf(f.w);
        const u16 l0 = f2bf(f.x - bf2f(h0)), l1 = f2bf(f.y - bf2f(h1));
        const u16 l2 = f2bf(f.z - bf2f(h2)), l3 = f2bf(f.w - bf2f(h3));
        uint2 H, L;
        H.x = (u32)h0 | ((u32)h1 << 16);  H.y = (u32)h2 | ((u32)h3 << 16);
        L.x = (u32)l0 | ((u32)l1 << 16);  L.y = (u32)l2 | ((u32)l3 << 16);
        *(uint2*)(dh + (size_t)off * 4) = H;
        *(uint2*)(dl + (size_t)off * 4) = L;
    }
}

// ---------------------------------------------------------------------------
// Split-bf16 MFMA QKV projection. Emits hi/lo bf16 pairs:
//   z=0: q = (xWq^T+bq)*0.125  -> [B,H,P,Dh]   (1/8 folded in)
//   z=1: k                      -> [B,H,P,Dh]
//   z=2: v TRANSPOSED           -> [B,H,Dh,P]  (PV B-operand wants V columns)
// ---------------------------------------------------------------------------
__global__ __launch_bounds__(256, 2)
void qkv_mfma(const u16* __restrict__ xh, const u16* __restrict__ xl,
              const u16* __restrict__ Wqh, const u16* __restrict__ Wql,
              const u16* __restrict__ Wkh, const u16* __restrict__ Wkl,
              const u16* __restrict__ Wvh, const u16* __restrict__ Wvl,
              const float* __restrict__ bq, const float* __restrict__ bk,
              const float* __restrict__ bv,
              u16* __restrict__ qoh, u16* __restrict__ qol,
              u16* __restrict__ koh, u16* __restrict__ kol,
              u16* __restrict__ vth, u16* __restrict__ vtl)
{
    __shared__ u16 Ah[4096], Al[4096], Bh[4096], Bl[4096];   // 4 x [128][32] bf16

    const int bm = blockIdx.x;
    const int n0 = blockIdx.y * 128;
    const int z  = blockIdx.z;
    const u16*  Wh   = (z == 0) ? Wqh : (z == 1) ? Wkh : Wvh;
    const u16*  Wl   = (z == 0) ? Wql : (z == 1) ? Wkl : Wvl;
    const float* bias = (z == 0) ? bq : (z == 1) ? bk : bv;
    u16* outh = (z == 0) ? qoh : (z == 1) ? koh : vth;
    u16* outl = (z == 0) ? qol : (z == 1) ? kol : vtl;
    const float sc = (z == 0) ? 0.125f : 1.0f;

    const int t = threadIdx.x, w = t >> 6, lane = t & 63;
    const int lr = lane >> 2, lk = lane & 3;
    const int wr = w >> 1, wc = w & 1;
    const int fr = lane & 15, fq = lane >> 4;

    const u16* aSh = xh + (size_t)(bm * 128 + w * 32 + lr) * DM_SZ + lk * 8;
    const u16* aSl = xl + (size_t)(bm * 128 + w * 32 + lr) * DM_SZ + lk * 8;
    const u16* bSh = Wh + (size_t)(n0 + w * 32 + lr) * DM_SZ + lk * 8;
    const u16* bSl = Wl + (size_t)(n0 + w * 32 + lr) * DM_SZ + lk * 8;
    u16* dAh = &Ah[w * 1024]; u16* dAl = &Al[w * 1024];
    u16* dBh = &Bh[w * 1024]; u16* dBl = &Bl[w * 1024];

    const int aoff = (wr * 64 + fr) * 32 + fq * 8;
    const int boff = (wc * 64 + fr) * 32 + fq * 8;

    f32x4 acc[4][4];
    #pragma unroll
    for (int i = 0; i < 4; ++i)
        #pragma unroll
        for (int j = 0; j < 4; ++j) acc[i][j] = (f32x4)0.f;

    for (int kt = 0; kt < DM_SZ / 32; ++kt) {
        const int ko_ = kt * 32;
        __syncthreads();
        gload16(aSh + ko_, dAh); gload16(aSh + ko_ + 16 * DM_SZ, dAh + 512);
        gload16(aSl + ko_, dAl); gload16(aSl + ko_ + 16 * DM_SZ, dAl + 512);
        gload16(bSh + ko_, dBh); gload16(bSh + ko_ + 16 * DM_SZ, dBh + 512);
        gload16(bSl + ko_, dBl); gload16(bSl + ko_ + 16 * DM_SZ, dBl + 512);
        __syncthreads();

        bf16x8 fah[4], fal[4], fbh[4], fbl[4];
        #pragma unroll
        for (int f = 0; f < 4; ++f) {
            fah[f] = *(const bf16x8*)&Ah[aoff + f * 512];
            fal[f] = *(const bf16x8*)&Al[aoff + f * 512];
            fbh[f] = *(const bf16x8*)&Bh[boff + f * 512];
            fbl[f] = *(const bf16x8*)&Bl[boff + f * 512];
        }
        #pragma unroll
        for (int i = 0; i < 4; ++i)
            #pragma unroll
            for (int j = 0; j < 4; ++j) {
                acc[i][j] = __builtin_amdgcn_mfma_f32_16x16x32_bf16(fah[i], fbh[j], acc[i][j], 0, 0, 0);
                acc[i][j] = __builtin_amdgcn_mfma_f32_16x16x32_bf16(fah[i], fbl[j], acc[i][j], 0, 0, 0);
                acc[i][j] = __builtin_amdgcn_mfma_f32_16x16x32_bf16(fal[i], fbh[j], acc[i][j], 0, 0, 0);
            }
    }

    #pragma unroll
    for (int i = 0; i < 4; ++i) {
        const int rbase = bm * 128 + wr * 64 + i * 16 + fq * 4;
        #pragma unroll
        for (int j = 0; j < 4; ++j) {
            const int n  = n0 + wc * 64 + j * 16 + fr;
            const float bb = bias[n];
            const int hh = n >> 6, dd = n & 63;
            #pragma unroll
            for (int r = 0; r < 4; ++r) {
                const int m = rbase + r;
                const int b = m >> 11, p = m & 2047;
                const float val = (acc[i][j][r] + bb) * sc;
                const size_t oidx = (z == 2)
                    ? (((size_t)(b * H_SZ + hh)) * DH_SZ + dd) * P_SZ + p
                    : (((size_t)(b * H_SZ + hh)) * P_SZ + p) * DH_SZ + dd;
                const u16 hv = f2bf(val);
                outh[oidx] = hv;
                outl[oidx] = f2bf(val - bf2f(hv));
            }
        }
    }
}

// ---------------------------------------------------------------------------
// Banded flash attention on MFMA (split-bf16 3-term => ~fp32 precision).
// Block = (b, h, q-tile of 64). 4 waves x 16-row strips. Chunks: |i-j|<=64.
// K/V staged via global_load_lds with pre-swizzled SOURCE (linear LDS dest,
// content swizzled col8 ^= row&7); reads XOR the same pattern -> 2-way free.
// Bias: log(e^{-d}+1e-12) ~= -d (error <=1e-9 of softmax mass).
// ---------------------------------------------------------------------------
__global__ __launch_bounds__(256, 3)
void attn_mfma(const u16* __restrict__ qh, const u16* __restrict__ ql,
               const u16* __restrict__ kh, const u16* __restrict__ kl,
               const u16* __restrict__ vth, const u16* __restrict__ vtl,
               const float* __restrict__ pmask,
               u16* __restrict__ aoh, u16* __restrict__ aol)
{
    __shared__ u16 Kh[4096], Kl[4096], Vh[4096], Vl[4096], Ph[4096], Pl[4096];

    const int bid = blockIdx.x;           // 2048 = B*H*32
    const int qt = bid & 31, bh = bid >> 5, b = bh >> 4, h = bh & 15;
    const int q0 = qt * 64;
    const int t = threadIdx.x, w = t >> 6, lane = t & 63;
    const int fr = lane & 15, fq = lane >> 4;

    // Q fragments (A-frag row = fr => global row q0+16w+fr), hi/lo, ks=0/1
    const size_t qrowbase = ((size_t)bh * P_SZ + q0 + 16 * w + fr) * DH_SZ + fq * 8;
    bf16x8 qfh[2], qfl[2];
    qfh[0] = *(const bf16x8*)(qh + qrowbase);
    qfh[1] = *(const bf16x8*)(qh + qrowbase + 32);
    qfl[0] = *(const bf16x8*)(ql + qrowbase);
    qfl[1] = *(const bf16x8*)(ql + qrowbase + 32);

    f32x4 o[4];
    #pragma unroll
    for (int j = 0; j < 4; ++j) o[j] = (f32x4)0.f;
    float m_run[4] = {-1e30f, -1e30f, -1e30f, -1e30f};
    float l_run[4] = {0.f, 0.f, 0.f, 0.f};

    // staging: lane covers (row = base + lane>>3, col8pos = lane&7); source col
    // pre-swizzled so LDS position col8 holds data column (col8 ^ (row&7)).
    const int sl8  = lane >> 3;
    const int scol = ((lane & 7) ^ sl8) * 8;
    const int swz  = (fr & 7) << 3;        // u16-index XOR for frag reads

    for (int ci = -1; ci <= 1; ++ci) {
        const int ct = qt + ci;
        if (ct < 0 || ct > 31) continue;
        const int c0 = ct * 64;

        __syncthreads();                   // prev chunk fully consumed
        #pragma unroll
        for (int i = 0; i < 2; ++i) {
            const int r8 = w * 16 + i * 8;
            const int row = r8 + sl8;
            const size_t ksrc = ((size_t)bh * P_SZ + c0 + row) * DH_SZ + scol;
            const size_t vsrc = ((size_t)bh * DH_SZ + row) * P_SZ + c0 + scol;
            gload16(kh + ksrc, &Kh[r8 * 64]);
            gload16(kl + ksrc, &Kl[r8 * 64]);
            gload16(vth + vsrc, &Vh[r8 * 64]);
            gload16(vtl + vsrc, &Vl[r8 * 64]);
        }
        __syncthreads();                   // vmcnt(0) drained before barrier

        // S = (Q/8) K^T, C layout: row(q) = 4*fq+r, col(k) = fr
        f32x4 s[4];
        #pragma unroll
        for (int j = 0; j < 4; ++j) s[j] = (f32x4)0.f;
        #pragma unroll
        for (int j = 0; j < 4; ++j) {
            const int krow = 16 * j + fr;
            #pragma unroll
            for (int ks = 0; ks < 2; ++ks) {
                const int ka = (krow * 64 + fq * 8 + 32 * ks) ^ swz;
                const bf16x8 kfh = *(const bf16x8*)&Kh[ka];
                const bf16x8 kfl = *(const bf16x8*)&Kl[ka];
                s[j] = __builtin_amdgcn_mfma_f32_16x16x32_bf16(qfh[ks], kfh, s[j], 0, 0, 0);
                s[j] = __builtin_amdgcn_mfma_f32_16x16x32_bf16(qfh[ks], kfl, s[j], 0, 0, 0);
                s[j] = __builtin_amdgcn_mfma_f32_16x16x32_bf16(qfl[ks], kfh, s[j], 0, 0, 0);
            }
        }

        // + time bias (-|dp|) + key padding mask
        float pm[4];
        #pragma unroll
        for (int j = 0; j < 4; ++j)
            pm[j] = (pmask[b * P_SZ + c0 + 16 * j + fr] > 0.f) ? 0.f : -1e9f;
        #pragma unroll
        for (int j = 0; j < 4; ++j)
            #pragma unroll
            for (int r = 0; r < 4; ++r) {
                const int diff = (q0 + 16 * w + 4 * fq + r) - (c0 + 16 * j + fr);
                s[j][r] += pm[j] - fabsf((float)diff);
            }

        // online softmax (row stats across fr-lanes via shfl_xor 1/2/4/8)
        float scale_[4], lloc[4];
        #pragma unroll
        for (int r = 0; r < 4; ++r) {
            float ml = fmaxf(fmaxf(s[0][r], s[1][r]), fmaxf(s[2][r], s[3][r]));
            ml = fmaxf(ml, __shfl_xor(ml, 1));
            ml = fmaxf(ml, __shfl_xor(ml, 2));
            ml = fmaxf(ml, __shfl_xor(ml, 4));
            ml = fmaxf(ml, __shfl_xor(ml, 8));
            const float mnew = fmaxf(m_run[r], ml);
            scale_[r] = __expf(m_run[r] - mnew);
            m_run[r] = mnew;
            lloc[r] = 0.f;
        }
        #pragma unroll
        for (int j = 0; j < 4; ++j)
            #pragma unroll
            for (int r = 0; r < 4; ++r) {
                const float p = __expf(s[j][r] - m_run[r]);
                s[j][r] = p;
                lloc[r] += p;
            }
        #pragma unroll
        for (int r = 0; r < 4; ++r) {
            float ll = lloc[r];
            ll += __shfl_xor(ll, 1);
            ll += __shfl_xor(ll, 2);
            ll += __shfl_xor(ll, 4);
            ll += __shfl_xor(ll, 8);
            l_run[r] = l_run[r] * scale_[r] + ll;
            o[0][r] *= scale_[r]; o[1][r] *= scale_[r];
            o[2][r] *= scale_[r]; o[3][r] *= scale_[r];
        }

        // P -> LDS hi/lo (swizzled; rows are wave-private: no barrier needed,
        // same-wave LDS ops execute in program order)
        #pragma unroll
        for (int j = 0; j < 4; ++j)
            #pragma unroll
            for (int r = 0; r < 4; ++r) {
                const int prow = 16 * w + 4 * fq + r;
                const int idx = (prow * 64 + 16 * j + fr) ^ ((prow & 7) << 3);
                const float p = s[j][r];
                const u16 hv = f2bf(p);
                Ph[idx] = hv;
                Pl[idx] = f2bf(p - bf2f(hv));
            }

        // O += P V  (A = P rows fr of this wave's strip; B = Vt rows d)
        const int prow = 16 * w + fr;
        #pragma unroll
        for (int ks = 0; ks < 2; ++ks) {
            const int pa = (prow * 64 + fq * 8 + 32 * ks) ^ swz;
            const bf16x8 pah = *(const bf16x8*)&Ph[pa];
            const bf16x8 pal = *(const bf16x8*)&Pl[pa];
            #pragma unroll
            for (int jd = 0; jd < 4; ++jd) {
                const int va = ((16 * jd + fr) * 64 + fq * 8 + 32 * ks) ^ swz;
                const bf16x8 vfh = *(const bf16x8*)&Vh[va];
                const bf16x8 vfl = *(const bf16x8*)&Vl[va];
                o[jd] = __builtin_amdgcn_mfma_f32_16x16x32_bf16(pah, vfh, o[jd], 0, 0, 0);
                o[jd] = __builtin_amdgcn_mfma_f32_16x16x32_bf16(pah, vfl, o[jd], 0, 0, 0);
                o[jd] = __builtin_amdgcn_mfma_f32_16x16x32_bf16(pal, vfh, o[jd], 0, 0, 0);
            }
        }
    }

    // normalize, emit ao hi/lo at [B,P,H*Dh] for the split-bf16 O-projection
    #pragma unroll
    for (int r = 0; r < 4; ++r) {
        const float inv = 1.0f / l_run[r];
        const int p = q0 + 16 * w + 4 * fq + r;
        #pragma unroll
        for (int jd = 0; jd < 4; ++jd) {
            const float val = o[jd][r] * inv;
            const size_t idx = ((size_t)(b * P_SZ + p)) * DM_SZ + h * DH_SZ + 16 * jd + fr;
            const u16 hv = f2bf(val);
            aoh[idx] = hv;
            aol[idx] = f2bf(val - bf2f(hv));
        }
    }
}

// ---------------------------------------------------------------------------
// O-projection: out = (ao @ Wo^T + bo) * patch_mask, split-bf16 3-term.
// ---------------------------------------------------------------------------
__global__ __launch_bounds__(256, 2)
void o_mfma(const u16* __restrict__ aoh, const u16* __restrict__ aol,
            const u16* __restrict__ Woh, const u16* __restrict__ Wol,
            const float* __restrict__ bo, const float* __restrict__ pmask,
            float* __restrict__ outp)
{
    __shared__ u16 Ah[4096], Al[4096], Bh[4096], Bl[4096];

    const int bm = blockIdx.x;
    const int n0 = blockIdx.y * 128;
    const int t = threadIdx.x, w = t >> 6, lane = t & 63;
    const int lr = lane >> 2, lk = lane & 3;
    const int wr = w >> 1, wc = w & 1;
    const int fr = lane & 15, fq = lane >> 4;

    const u16* aSh = aoh + (size_t)(bm * 128 + w * 32 + lr) * DM_SZ + lk * 8;
    const u16* aSl = aol + (size_t)(bm * 128 + w * 32 + lr) * DM_SZ + lk * 8;
    const u16* bSh = Woh + (size_t)(n0 + w * 32 + lr) * DM_SZ + lk * 8;
    const u16* bSl = Wol + (size_t)(n0 + w * 32 + lr) * DM_SZ + lk * 8;
    u16* dAh = &Ah[w * 1024]; u16* dAl = &Al[w * 1024];
    u16* dBh = &Bh[w * 1024]; u16* dBl = &Bl[w * 1024];

    const int aoff = (wr * 64 + fr) * 32 + fq * 8;
    const int boff = (wc * 64 + fr) * 32 + fq * 8;

    f32x4 acc[4][4];
    #pragma unroll
    for (int i = 0; i < 4; ++i)
        #pragma unroll
        for (int j = 0; j < 4; ++j) acc[i][j] = (f32x4)0.f;

    for (int kt = 0; kt < DM_SZ / 32; ++kt) {
        const int ko_ = kt * 32;
        __syncthreads();
        gload16(aSh + ko_, dAh); gload16(aSh + ko_ + 16 * DM_SZ, dAh + 512);
        gload16(aSl + ko_, dAl); gload16(aSl + ko_ + 16 * DM_SZ, dAl + 512);
        gload16(bSh + ko_, dBh); gload16(bSh + ko_ + 16 * DM_SZ, dBh + 512);
        gload16(bSl + ko_, dBl); gload16(bSl + ko_ + 16 * DM_SZ, dBl + 512);
        __syncthreads();

        bf16x8 fah[4], fal[4], fbh[4], fbl[4];
        #pragma unroll
        for (int f = 0; f < 4; ++f) {
            fah[f] = *(const bf16x8*)&Ah[aoff + f * 512];
            fal[f] = *(const bf16x8*)&Al[aoff + f * 512];
            fbh[f] = *(const bf16x8*)&Bh[boff + f * 512];
            fbl[f] = *(const bf16x8*)&Bl[boff + f * 512];
        }
        #pragma unroll
        for (int i = 0; i < 4; ++i)
            #pragma unroll
            for (int j = 0; j < 4; ++j) {
                acc[i][j] = __builtin_amdgcn_mfma_f32_16x16x32_bf16(fah[i], fbh[j], acc[i][j], 0, 0, 0);
                acc[i][j] = __builtin_amdgcn_mfma_f32_16x16x32_bf16(fah[i], fbl[j], acc[i][j], 0, 0, 0);
                acc[i][j] = __builtin_amdgcn_mfma_f32_16x16x32_bf16(fal[i], fbh[j], acc[i][j], 0, 0, 0);
            }
    }

    #pragma unroll
    for (int i = 0; i < 4; ++i) {
        const int rbase = bm * 128 + wr * 64 + i * 16 + fq * 4;
        #pragma unroll
        for (int j = 0; j < 4; ++j) {
            const int n  = n0 + wc * 64 + j * 16 + fr;
            const float bb = bo[n];
            #pragma unroll
            for (int r = 0; r < 4; ++r) {
                const int m = rbase + r;
                outp[(size_t)m * DM_SZ + n] = (acc[i][j][r] + bb) * pmask[m];
            }
        }
    }
}

// ===========================================================================
extern "C" void kernel_launch(void* const* d_in, const int* in_sizes, int n_in,
                              void* d_out, int out_size, void* d_ws, size_t ws_size,
                              hipStream_t stream)
{
    const float* x     = (const float*)d_in[0];
    const float* pmask = (const float*)d_in[1];
    const float* Wq    = (const float*)d_in[2];
    const float* bq    = (const float*)d_in[3];
    const float* Wk    = (const float*)d_in[4];
    const float* bk    = (const float*)d_in[5];
    const float* Wv    = (const float*)d_in[6];
    const float* bv    = (const float*)d_in[7];
    const float* Wo    = (const float*)d_in[8];
    const float* bo    = (const float*)d_in[9];

    // ws layout — 112 MiB:
    //  xh,xl     2 x 8.4M u16 = 32 MiB   (reused as aoh/aol after qkv_mfma)
    //  W splits  8 x 1M  u16 = 16 MiB
    //  q hi/lo   2 x 8.4M u16 = 32 MiB
    //  k hi/lo   2 x 8.4M u16 = 32 MiB
    // V^T hi/lo (32 MiB) lives in d_out: written by qkv_mfma, read by attn,
    // then o_mfma fully overwrites d_out last (stream-ordered, no overlap).
    u16* xh  = (u16*)d_ws;
    u16* xl  = xh + (size_t)QKV_ELEMS;
    u16* wqh = xl + (size_t)QKV_ELEMS;
    u16* wql = wqh + 1048576;
    u16* wkh = wql + 1048576;
    u16* wkl = wkh + 1048576;
    u16* wvh = wkl + 1048576;
    u16* wvl = wvh + 1048576;
    u16* woh = wvl + 1048576;
    u16* wol = woh + 1048576;
    u16* qh_ = wol + 1048576;
    u16* ql_ = qh_ + (size_t)QKV_ELEMS;
    u16* kh_ = ql_ + (size_t)QKV_ELEMS;
    u16* kl_ = kh_ + (size_t)QKV_ELEMS;
    u16* vth = (u16*)d_out;
    u16* vtl = vth + (size_t)QKV_ELEMS;
    u16* aoh = xh;
    u16* aol = xl;

    split_inputs<<<dim3(1024), 256, 0, stream>>>(
        (const float4*)x, (const float4*)Wq, (const float4*)Wk,
        (const float4*)Wv, (const float4*)Wo,
        xh, xl, wqh, wql, wkh, wkl, wvh, wvl, woh, wol);

    qkv_mfma<<<dim3(64, 8, 3), 256, 0, stream>>>(
        xh, xl, wqh, wql, wkh, wkl, wvh, wvl, bq, bk, bv,
        qh_, ql_, kh_, kl_, vth, vtl);

    attn_mfma<<<dim3(2048), 256, 0, stream>>>(
        qh_, ql_, kh_, kl_, vth, vtl, pmask, aoh, aol);

    o_mfma<<<dim3(64, 8), 256, 0, stream>>>(aoh, aol, woh, wol, bo, pmask, (float*)d_out);
}

// Round 10
// 256.811 us; speedup vs baseline: 3.9991x; 1.5009x over previous
//
#include <hip/hip_runtime.h>
#include <math.h>

typedef unsigned short u16;
typedef unsigned int   u32;
typedef __attribute__((ext_vector_type(8))) _Float16 f16x8;  // 4 VGPRs, MFMA A/B frag
typedef __attribute__((ext_vector_type(4))) float    f32x4;  // MFMA C/D frag

#define B_SZ   4
#define P_SZ   2048
#define H_SZ   16
#define DH_SZ  64
#define DM_SZ  1024
#define QKV_ELEMS (B_SZ * H_SZ * P_SZ * DH_SZ)  // 8388608

// ---------------------------------------------------------------------------
__device__ __forceinline__ u16 f2h(float f) {
    const _Float16 h = (_Float16)f;          // v_cvt_f16_f32, RNE
    return __builtin_bit_cast(u16, h);
}
__device__ __forceinline__ void gload16(const u16* g, u16* l) {
    __builtin_amdgcn_global_load_lds((const __attribute__((address_space(1))) void*)g,
                                     (__attribute__((address_space(3))) void*)l,
                                     16, 0, 0);
}

// ---------------------------------------------------------------------------
// Cast fp32 -> fp16 for x and the 4 weight matrices (single term, no split).
// ---------------------------------------------------------------------------
__global__ __launch_bounds__(256)
void cast_inputs(const float4* __restrict__ x4,
                 const float4* __restrict__ wq4, const float4* __restrict__ wk4,
                 const float4* __restrict__ wv4, const float4* __restrict__ wo4,
                 u16* __restrict__ xc, u16* __restrict__ qc, u16* __restrict__ kc,
                 u16* __restrict__ vc, u16* __restrict__ oc)
{
    const int total4 = 3145728;     // (8388608 + 4*1048576)/4
    for (int i = blockIdx.x * blockDim.x + threadIdx.x; i < total4;
         i += gridDim.x * blockDim.x) {
        const float4* src; u16* d; int off;
        if (i < 2097152) { src = x4; d = xc; off = i; }
        else {
            const int j = i - 2097152;
            const int r = j >> 18;            // which W (262144 float4 each)
            off = j & 262143;
            switch (r) {
                case 0:  src = wq4; d = qc; break;
                case 1:  src = wk4; d = kc; break;
                case 2:  src = wv4; d = vc; break;
                default: src = wo4; d = oc; break;
            }
        }
        const float4 f = src[off];
        uint2 H;
        H.x = (u32)f2h(f.x) | ((u32)f2h(f.y) << 16);
        H.y = (u32)f2h(f.z) | ((u32)f2h(f.w) << 16);
        *(uint2*)(d + (size_t)off * 4) = H;
    }
}

// ---------------------------------------------------------------------------
// fp16 MFMA QKV projection (single term). Emits fp16:
//   z=0: q = (xWq^T+bq)*0.125  -> [B,H,P,Dh]   (1/8 folded in)
//   z=1: k                      -> [B,H,P,Dh]
//   z=2: v TRANSPOSED           -> [B,H,Dh,P]  (PV B-operand wants V columns)
// m97 structure: 128x128 tile, BK=32, 4 waves (2x2 of 64x64), 2-barrier K-loop,
// global_load_lds width 16. 16 MFMA : 4 gload per K-step per wave.
// ---------------------------------------------------------------------------
__global__ __launch_bounds__(256, 2)
void qkv_mfma(const u16* __restrict__ xc,
              const u16* __restrict__ Wq, const u16* __restrict__ Wk,
              const u16* __restrict__ Wv,
              const float* __restrict__ bq, const float* __restrict__ bk,
              const float* __restrict__ bv,
              u16* __restrict__ qo, u16* __restrict__ ko, u16* __restrict__ vto)
{
    __shared__ u16 As[4096], Bs[4096];   // 2 x [128][32] fp16

    const int bm = blockIdx.x;
    const int n0 = blockIdx.y * 128;
    const int z  = blockIdx.z;
    const u16*  W    = (z == 0) ? Wq : (z == 1) ? Wk : Wv;
    const float* bias = (z == 0) ? bq : (z == 1) ? bk : bv;
    u16* out          = (z == 0) ? qo : (z == 1) ? ko : vto;
    const float sc   = (z == 0) ? 0.125f : 1.0f;

    const int t = threadIdx.x, w = t >> 6, lane = t & 63;
    const int lr = lane >> 2, lk = lane & 3;
    const int wr = w >> 1, wc = w & 1;
    const int fr = lane & 15, fq = lane >> 4;

    const u16* aS = xc + (size_t)(bm * 128 + w * 32 + lr) * DM_SZ + lk * 8;
    const u16* bS = W  + (size_t)(n0 + w * 32 + lr) * DM_SZ + lk * 8;
    u16* dA = &As[w * 1024];
    u16* dB = &Bs[w * 1024];

    const int aoff = (wr * 64 + fr) * 32 + fq * 8;
    const int boff = (wc * 64 + fr) * 32 + fq * 8;

    f32x4 acc[4][4];
    #pragma unroll
    for (int i = 0; i < 4; ++i)
        #pragma unroll
        for (int j = 0; j < 4; ++j) acc[i][j] = (f32x4)0.f;

    for (int kt = 0; kt < DM_SZ / 32; ++kt) {
        const int ko_ = kt * 32;
        __syncthreads();
        gload16(aS + ko_, dA); gload16(aS + ko_ + 16 * DM_SZ, dA + 512);
        gload16(bS + ko_, dB); gload16(bS + ko_ + 16 * DM_SZ, dB + 512);
        __syncthreads();

        f16x8 fa[4], fb[4];
        #pragma unroll
        for (int f = 0; f < 4; ++f) {
            fa[f] = *(const f16x8*)&As[aoff + f * 512];
            fb[f] = *(const f16x8*)&Bs[boff + f * 512];
        }
        #pragma unroll
        for (int i = 0; i < 4; ++i)
            #pragma unroll
            for (int j = 0; j < 4; ++j)
                acc[i][j] = __builtin_amdgcn_mfma_f32_16x16x32_f16(fa[i], fb[j], acc[i][j], 0, 0, 0);
    }

    #pragma unroll
    for (int i = 0; i < 4; ++i) {
        const int rbase = bm * 128 + wr * 64 + i * 16 + fq * 4;
        #pragma unroll
        for (int j = 0; j < 4; ++j) {
            const int n  = n0 + wc * 64 + j * 16 + fr;
            const float bb = bias[n];
            const int hh = n >> 6, dd = n & 63;
            #pragma unroll
            for (int r = 0; r < 4; ++r) {
                const int m = rbase + r;
                const int b = m >> 11, p = m & 2047;
                const float val = (acc[i][j][r] + bb) * sc;
                const size_t oidx = (z == 2)
                    ? (((size_t)(b * H_SZ + hh)) * DH_SZ + dd) * P_SZ + p
                    : (((size_t)(b * H_SZ + hh)) * P_SZ + p) * DH_SZ + dd;
                out[oidx] = f2h(val);
            }
        }
    }
}

// ---------------------------------------------------------------------------
// Banded flash attention on fp16 MFMA (single term).
// Block = (b, h, q-tile of 64). 4 waves x 16-row strips. Chunks: |i-j|<=64.
// K/V staged via global_load_lds with pre-swizzled SOURCE (linear LDS dest,
// content swizzled col8 ^= row&7); reads XOR the same pattern -> 2-way free.
// Bias: log(e^{-d}+1e-12) ~= -d (error <=1e-9 of softmax mass).
// ---------------------------------------------------------------------------
__global__ __launch_bounds__(256, 4)
void attn_mfma(const u16* __restrict__ qc, const u16* __restrict__ kc,
               const u16* __restrict__ vtc, const float* __restrict__ pmask,
               u16* __restrict__ aoc)
{
    __shared__ u16 Ks[4096], Vs[4096], Ps[4096];

    const int bid = blockIdx.x;           // 2048 = B*H*32
    const int qt = bid & 31, bh = bid >> 5, b = bh >> 4, h = bh & 15;
    const int q0 = qt * 64;
    const int t = threadIdx.x, w = t >> 6, lane = t & 63;
    const int fr = lane & 15, fq = lane >> 4;

    // Q fragments (A-frag row = fr => global row q0+16w+fr), ks=0/1
    const size_t qrowbase = ((size_t)bh * P_SZ + q0 + 16 * w + fr) * DH_SZ + fq * 8;
    f16x8 qf[2];
    qf[0] = *(const f16x8*)(qc + qrowbase);
    qf[1] = *(const f16x8*)(qc + qrowbase + 32);

    f32x4 o[4];
    #pragma unroll
    for (int j = 0; j < 4; ++j) o[j] = (f32x4)0.f;
    float m_run[4] = {-1e30f, -1e30f, -1e30f, -1e30f};
    float l_run[4] = {0.f, 0.f, 0.f, 0.f};

    // staging: lane covers (row = base + lane>>3, col8pos = lane&7); source col
    // pre-swizzled so LDS position col8 holds data column (col8 ^ (row&7)).
    const int sl8  = lane >> 3;
    const int scol = ((lane & 7) ^ sl8) * 8;
    const int swz  = (fr & 7) << 3;        // u16-index XOR for frag reads

    for (int ci = -1; ci <= 1; ++ci) {
        const int ct = qt + ci;
        if (ct < 0 || ct > 31) continue;
        const int c0 = ct * 64;

        __syncthreads();                   // prev chunk fully consumed
        #pragma unroll
        for (int i = 0; i < 2; ++i) {
            const int r8 = w * 16 + i * 8;
            const int row = r8 + sl8;
            const size_t ksrc = ((size_t)bh * P_SZ + c0 + row) * DH_SZ + scol;
            const size_t vsrc = ((size_t)bh * DH_SZ + row) * P_SZ + c0 + scol;
            gload16(kc + ksrc, &Ks[r8 * 64]);
            gload16(vtc + vsrc, &Vs[r8 * 64]);
        }
        __syncthreads();                   // vmcnt(0) drained before barrier

        // S = (Q/8) K^T, C layout: row(q) = 4*fq+r, col(k) = fr
        f32x4 s[4];
        #pragma unroll
        for (int j = 0; j < 4; ++j) s[j] = (f32x4)0.f;
        #pragma unroll
        for (int j = 0; j < 4; ++j) {
            const int krow = 16 * j + fr;
            #pragma unroll
            for (int ks = 0; ks < 2; ++ks) {
                const int ka = (krow * 64 + fq * 8 + 32 * ks) ^ swz;
                const f16x8 kf = *(const f16x8*)&Ks[ka];
                s[j] = __builtin_amdgcn_mfma_f32_16x16x32_f16(qf[ks], kf, s[j], 0, 0, 0);
            }
        }

        // + time bias (-|dp|) + key padding mask
        float pm[4];
        #pragma unroll
        for (int j = 0; j < 4; ++j)
            pm[j] = (pmask[b * P_SZ + c0 + 16 * j + fr] > 0.f) ? 0.f : -1e9f;
        #pragma unroll
        for (int j = 0; j < 4; ++j)
            #pragma unroll
            for (int r = 0; r < 4; ++r) {
                const int diff = (q0 + 16 * w + 4 * fq + r) - (c0 + 16 * j + fr);
                s[j][r] += pm[j] - fabsf((float)diff);
            }

        // online softmax (row stats across fr-lanes via shfl_xor 1/2/4/8)
        float scale_[4], lloc[4];
        #pragma unroll
        for (int r = 0; r < 4; ++r) {
            float ml = fmaxf(fmaxf(s[0][r], s[1][r]), fmaxf(s[2][r], s[3][r]));
            ml = fmaxf(ml, __shfl_xor(ml, 1));
            ml = fmaxf(ml, __shfl_xor(ml, 2));
            ml = fmaxf(ml, __shfl_xor(ml, 4));
            ml = fmaxf(ml, __shfl_xor(ml, 8));
            const float mnew = fmaxf(m_run[r], ml);
            scale_[r] = __expf(m_run[r] - mnew);
            m_run[r] = mnew;
            lloc[r] = 0.f;
        }
        #pragma unroll
        for (int j = 0; j < 4; ++j)
            #pragma unroll
            for (int r = 0; r < 4; ++r) {
                const float p = __expf(s[j][r] - m_run[r]);
                s[j][r] = p;
                lloc[r] += p;
            }
        #pragma unroll
        for (int r = 0; r < 4; ++r) {
            float ll = lloc[r];
            ll += __shfl_xor(ll, 1);
            ll += __shfl_xor(ll, 2);
            ll += __shfl_xor(ll, 4);
            ll += __shfl_xor(ll, 8);
            l_run[r] = l_run[r] * scale_[r] + ll;
            o[0][r] *= scale_[r]; o[1][r] *= scale_[r];
            o[2][r] *= scale_[r]; o[3][r] *= scale_[r];
        }

        // P -> LDS fp16 (swizzled; rows are wave-private: no barrier needed,
        // same-wave LDS ops execute in program order)
        #pragma unroll
        for (int j = 0; j < 4; ++j)
            #pragma unroll
            for (int r = 0; r < 4; ++r) {
                const int prow = 16 * w + 4 * fq + r;
                const int idx = (prow * 64 + 16 * j + fr) ^ ((prow & 7) << 3);
                Ps[idx] = f2h(s[j][r]);
            }

        // O += P V  (A = P rows fr of this wave's strip; B = Vt rows d)
        const int prow = 16 * w + fr;
        #pragma unroll
        for (int ks = 0; ks < 2; ++ks) {
            const int pa = (prow * 64 + fq * 8 + 32 * ks) ^ swz;
            const f16x8 pf = *(const f16x8*)&Ps[pa];
            #pragma unroll
            for (int jd = 0; jd < 4; ++jd) {
                const int va = ((16 * jd + fr) * 64 + fq * 8 + 32 * ks) ^ swz;
                const f16x8 vf = *(const f16x8*)&Vs[va];
                o[jd] = __builtin_amdgcn_mfma_f32_16x16x32_f16(pf, vf, o[jd], 0, 0, 0);
            }
        }
    }

    // normalize, emit ao fp16 at [B,P,H*Dh] for the O-projection
    #pragma unroll
    for (int r = 0; r < 4; ++r) {
        const float inv = 1.0f / l_run[r];
        const int p = q0 + 16 * w + 4 * fq + r;
        #pragma unroll
        for (int jd = 0; jd < 4; ++jd) {
            const float val = o[jd][r] * inv;
            const size_t idx = ((size_t)(b * P_SZ + p)) * DM_SZ + h * DH_SZ + 16 * jd + fr;
            aoc[idx] = f2h(val);
        }
    }
}

// ---------------------------------------------------------------------------
// O-projection: out = (ao @ Wo^T + bo) * patch_mask, fp16 single term.
// ---------------------------------------------------------------------------
__global__ __launch_bounds__(256, 2)
void o_mfma(const u16* __restrict__ aoc, const u16* __restrict__ Woc,
            const float* __restrict__ bo, const float* __restrict__ pmask,
            float* __restrict__ outp)
{
    __shared__ u16 As[4096], Bs[4096];

    const int bm = blockIdx.x;
    const int n0 = blockIdx.y * 128;
    const int t = threadIdx.x, w = t >> 6, lane = t & 63;
    const int lr = lane >> 2, lk = lane & 3;
    const int wr = w >> 1, wc = w & 1;
    const int fr = lane & 15, fq = lane >> 4;

    const u16* aS = aoc + (size_t)(bm * 128 + w * 32 + lr) * DM_SZ + lk * 8;
    const u16* bS = Woc + (size_t)(n0 + w * 32 + lr) * DM_SZ + lk * 8;
    u16* dA = &As[w * 1024];
    u16* dB = &Bs[w * 1024];

    const int aoff = (wr * 64 + fr) * 32 + fq * 8;
    const int boff = (wc * 64 + fr) * 32 + fq * 8;

    f32x4 acc[4][4];
    #pragma unroll
    for (int i = 0; i < 4; ++i)
        #pragma unroll
        for (int j = 0; j < 4; ++j) acc[i][j] = (f32x4)0.f;

    for (int kt = 0; kt < DM_SZ / 32; ++kt) {
        const int ko_ = kt * 32;
        __syncthreads();
        gload16(aS + ko_, dA); gload16(aS + ko_ + 16 * DM_SZ, dA + 512);
        gload16(bS + ko_, dB); gload16(bS + ko_ + 16 * DM_SZ, dB + 512);
        __syncthreads();

        f16x8 fa[4], fb[4];
        #pragma unroll
        for (int f = 0; f < 4; ++f) {
            fa[f] = *(const f16x8*)&As[aoff + f * 512];
            fb[f] = *(const f16x8*)&Bs[boff + f * 512];
        }
        #pragma unroll
        for (int i = 0; i < 4; ++i)
            #pragma unroll
            for (int j = 0; j < 4; ++j)
                acc[i][j] = __builtin_amdgcn_mfma_f32_16x16x32_f16(fa[i], fb[j], acc[i][j], 0, 0, 0);
    }

    #pragma unroll
    for (int i = 0; i < 4; ++i) {
        const int rbase = bm * 128 + wr * 64 + i * 16 + fq * 4;
        #pragma unroll
        for (int j = 0; j < 4; ++j) {
            const int n  = n0 + wc * 64 + j * 16 + fr;
            const float bb = bo[n];
            #pragma unroll
            for (int r = 0; r < 4; ++r) {
                const int m = rbase + r;
                outp[(size_t)m * DM_SZ + n] = (acc[i][j][r] + bb) * pmask[m];
            }
        }
    }
}

// ===========================================================================
extern "C" void kernel_launch(void* const* d_in, const int* in_sizes, int n_in,
                              void* d_out, int out_size, void* d_ws, size_t ws_size,
                              hipStream_t stream)
{
    const float* x     = (const float*)d_in[0];
    const float* pmask = (const float*)d_in[1];
    const float* Wq    = (const float*)d_in[2];
    const float* bq    = (const float*)d_in[3];
    const float* Wk    = (const float*)d_in[4];
    const float* bk    = (const float*)d_in[5];
    const float* Wv    = (const float*)d_in[6];
    const float* bv    = (const float*)d_in[7];
    const float* Wo    = (const float*)d_in[8];
    const float* bo    = (const float*)d_in[9];

    // ws layout — 75 MiB (well under the 112 MiB proven bound):
    //  xc        8.4M u16 = 16 MiB   (reused as aoc after qkv_mfma consumes it)
    //  W casts   4 x 1M u16 = 8 MiB
    //  qc,kc,vtc 3 x 8.4M u16 = 48 MiB
    u16* xc  = (u16*)d_ws;
    u16* wqc = xc + (size_t)QKV_ELEMS;
    u16* wkc = wqc + 1048576;
    u16* wvc = wkc + 1048576;
    u16* woc = wvc + 1048576;
    u16* qc  = woc + 1048576;
    u16* kc  = qc + (size_t)QKV_ELEMS;
    u16* vtc = kc + (size_t)QKV_ELEMS;
    u16* aoc = xc;   // x cast dead after qkv_mfma; stream order makes this safe

    cast_inputs<<<dim3(1024), 256, 0, stream>>>(
        (const float4*)x, (const float4*)Wq, (const float4*)Wk,
        (const float4*)Wv, (const float4*)Wo,
        xc, wqc, wkc, wvc, woc);

    qkv_mfma<<<dim3(64, 8, 3), 256, 0, stream>>>(
        xc, wqc, wkc, wvc, bq, bk, bv, qc, kc, vtc);

    attn_mfma<<<dim3(2048), 256, 0, stream>>>(
        qc, kc, vtc, pmask, aoc);

    o_mfma<<<dim3(64, 8), 256, 0, stream>>>(aoc, woc, bo, pmask, (float*)d_out);
}

// Round 11
// 249.381 us; speedup vs baseline: 4.1183x; 1.0298x over previous
//
#include <hip/hip_runtime.h>
#include <math.h>

typedef unsigned short u16;
typedef unsigned int   u32;
typedef __attribute__((ext_vector_type(8))) _Float16 f16x8;  // 4 VGPRs, MFMA A/B frag
typedef __attribute__((ext_vector_type(4))) float    f32x4;  // MFMA C/D frag

#define B_SZ   4
#define P_SZ   2048
#define H_SZ   16
#define DH_SZ  64
#define DM_SZ  1024
#define QKV_ELEMS (B_SZ * H_SZ * P_SZ * DH_SZ)  // 8388608

// ---------------------------------------------------------------------------
__device__ __forceinline__ u16 f2h(float f) {
    const _Float16 h = (_Float16)f;          // v_cvt_f16_f32, RNE
    return __builtin_bit_cast(u16, h);
}
__device__ __forceinline__ void gload16(const u16* g, u16* l) {
    __builtin_amdgcn_global_load_lds((const __attribute__((address_space(1))) void*)g,
                                     (__attribute__((address_space(3))) void*)l,
                                     16, 0, 0);
}

// ---------------------------------------------------------------------------
// Cast fp32 -> fp16 for x and the 4 weight matrices (single term, no split).
// ---------------------------------------------------------------------------
__global__ __launch_bounds__(256)
void cast_inputs(const float4* __restrict__ x4,
                 const float4* __restrict__ wq4, const float4* __restrict__ wk4,
                 const float4* __restrict__ wv4, const float4* __restrict__ wo4,
                 u16* __restrict__ xc, u16* __restrict__ qc, u16* __restrict__ kc,
                 u16* __restrict__ vc, u16* __restrict__ oc)
{
    const int total4 = 3145728;     // (8388608 + 4*1048576)/4
    for (int i = blockIdx.x * blockDim.x + threadIdx.x; i < total4;
         i += gridDim.x * blockDim.x) {
        const float4* src; u16* d; int off;
        if (i < 2097152) { src = x4; d = xc; off = i; }
        else {
            const int j = i - 2097152;
            const int r = j >> 18;            // which W (262144 float4 each)
            off = j & 262143;
            switch (r) {
                case 0:  src = wq4; d = qc; break;
                case 1:  src = wk4; d = kc; break;
                case 2:  src = wv4; d = vc; break;
                default: src = wo4; d = oc; break;
            }
        }
        const float4 f = src[off];
        uint2 H;
        H.x = (u32)f2h(f.x) | ((u32)f2h(f.y) << 16);
        H.y = (u32)f2h(f.z) | ((u32)f2h(f.w) << 16);
        *(uint2*)(d + (size_t)off * 4) = H;
    }
}

// ---------------------------------------------------------------------------
// fp16 MFMA QKV projection (single term). Emits fp16:
//   z=0: q = (xWq^T+bq)*0.125  -> [B,H,P,Dh]   (1/8 folded in)
//   z=1: k                      -> [B,H,P,Dh]
//   z=2: v TRANSPOSED           -> [B,H,Dh,P]  (PV B-operand wants V columns)
// ---------------------------------------------------------------------------
__global__ __launch_bounds__(256, 2)
void qkv_mfma(const u16* __restrict__ xc,
              const u16* __restrict__ Wq, const u16* __restrict__ Wk,
              const u16* __restrict__ Wv,
              const float* __restrict__ bq, const float* __restrict__ bk,
              const float* __restrict__ bv,
              u16* __restrict__ qo, u16* __restrict__ ko, u16* __restrict__ vto)
{
    __shared__ u16 As[4096], Bs[4096];   // 2 x [128][32] fp16

    const int bm = blockIdx.x;
    const int n0 = blockIdx.y * 128;
    const int z  = blockIdx.z;
    const u16*  W    = (z == 0) ? Wq : (z == 1) ? Wk : Wv;
    const float* bias = (z == 0) ? bq : (z == 1) ? bk : bv;
    u16* out          = (z == 0) ? qo : (z == 1) ? ko : vto;
    const float sc   = (z == 0) ? 0.125f : 1.0f;

    const int t = threadIdx.x, w = t >> 6, lane = t & 63;
    const int lr = lane >> 2, lk = lane & 3;
    const int wr = w >> 1, wc = w & 1;
    const int fr = lane & 15, fq = lane >> 4;

    const u16* aS = xc + (size_t)(bm * 128 + w * 32 + lr) * DM_SZ + lk * 8;
    const u16* bS = W  + (size_t)(n0 + w * 32 + lr) * DM_SZ + lk * 8;
    u16* dA = &As[w * 1024];
    u16* dB = &Bs[w * 1024];

    const int aoff = (wr * 64 + fr) * 32 + fq * 8;
    const int boff = (wc * 64 + fr) * 32 + fq * 8;

    f32x4 acc[4][4];
    #pragma unroll
    for (int i = 0; i < 4; ++i)
        #pragma unroll
        for (int j = 0; j < 4; ++j) acc[i][j] = (f32x4)0.f;

    for (int kt = 0; kt < DM_SZ / 32; ++kt) {
        const int ko_ = kt * 32;
        __syncthreads();
        gload16(aS + ko_, dA); gload16(aS + ko_ + 16 * DM_SZ, dA + 512);
        gload16(bS + ko_, dB); gload16(bS + ko_ + 16 * DM_SZ, dB + 512);
        __syncthreads();

        f16x8 fa[4], fb[4];
        #pragma unroll
        for (int f = 0; f < 4; ++f) {
            fa[f] = *(const f16x8*)&As[aoff + f * 512];
            fb[f] = *(const f16x8*)&Bs[boff + f * 512];
        }
        #pragma unroll
        for (int i = 0; i < 4; ++i)
            #pragma unroll
            for (int j = 0; j < 4; ++j)
                acc[i][j] = __builtin_amdgcn_mfma_f32_16x16x32_f16(fa[i], fb[j], acc[i][j], 0, 0, 0);
    }

    #pragma unroll
    for (int i = 0; i < 4; ++i) {
        const int rbase = bm * 128 + wr * 64 + i * 16 + fq * 4;
        #pragma unroll
        for (int j = 0; j < 4; ++j) {
            const int n  = n0 + wc * 64 + j * 16 + fr;
            const float bb = bias[n];
            const int hh = n >> 6, dd = n & 63;
            #pragma unroll
            for (int r = 0; r < 4; ++r) {
                const int m = rbase + r;
                const int b = m >> 11, p = m & 2047;
                const float val = (acc[i][j][r] + bb) * sc;
                const size_t oidx = (z == 2)
                    ? (((size_t)(b * H_SZ + hh)) * DH_SZ + dd) * P_SZ + p
                    : (((size_t)(b * H_SZ + hh)) * P_SZ + p) * DH_SZ + dd;
                out[oidx] = f2h(val);
            }
        }
    }
}

// ---------------------------------------------------------------------------
// Banded flash attention, fp16 MFMA — SINGLE-DRAIN version.
// All 3 chunks' K/V loads issue up front into a 3-chunk LDS arena; ONE
// vmcnt(0)+barrier; then all chunks compute with no further barriers
// (K/V read-only post-stage; P rows are wave-private, same-wave ordered —
// hardware-validated by rounds 9/10 passing with this P scheme).
// ---------------------------------------------------------------------------
__global__ __launch_bounds__(256, 2)
void attn_mfma(const u16* __restrict__ qc, const u16* __restrict__ kc,
               const u16* __restrict__ vtc, const float* __restrict__ pmask,
               u16* __restrict__ aoc)
{
    __shared__ u16 Ks[3 * 4096], Vs[3 * 4096], Ps[4096];   // 56 KB

    const int bid = blockIdx.x;           // 2048 = B*H*32
    const int qt = bid & 31, bh = bid >> 5, b = bh >> 4, h = bh & 15;
    const int q0 = qt * 64;
    const int t = threadIdx.x, w = t >> 6, lane = t & 63;
    const int fr = lane & 15, fq = lane >> 4;

    // Q fragments (A-frag row = fr => global row q0+16w+fr), ks=0/1
    const size_t qrowbase = ((size_t)bh * P_SZ + q0 + 16 * w + fr) * DH_SZ + fq * 8;
    f16x8 qf[2];
    qf[0] = *(const f16x8*)(qc + qrowbase);
    qf[1] = *(const f16x8*)(qc + qrowbase + 32);

    // stage ALL valid chunks, then one drain barrier
    const int sl8  = lane >> 3;
    const int scol = ((lane & 7) ^ sl8) * 8;   // pre-swizzled source col
    const int swz  = (fr & 7) << 3;            // u16-index XOR for frag reads

    #pragma unroll
    for (int cc = 0; cc < 3; ++cc) {
        const int ct = qt - 1 + cc;
        if (ct < 0 || ct > 31) continue;       // block-uniform predicate
        const int c0 = ct * 64;
        #pragma unroll
        for (int i = 0; i < 2; ++i) {
            const int r8 = w * 16 + i * 8;
            const int row = r8 + sl8;
            const size_t ksrc = ((size_t)bh * P_SZ + c0 + row) * DH_SZ + scol;
            const size_t vsrc = ((size_t)bh * DH_SZ + row) * P_SZ + c0 + scol;
            gload16(kc + ksrc, &Ks[cc * 4096 + r8 * 64]);
            gload16(vtc + vsrc, &Vs[cc * 4096 + r8 * 64]);
        }
    }
    __syncthreads();   // single vmcnt(0) drain + cross-wave visibility

    f32x4 o[4];
    #pragma unroll
    for (int j = 0; j < 4; ++j) o[j] = (f32x4)0.f;
    float m_run[4] = {-1e30f, -1e30f, -1e30f, -1e30f};
    float l_run[4] = {0.f, 0.f, 0.f, 0.f};

    #pragma unroll
    for (int cc = 0; cc < 3; ++cc) {
        const int ct = qt - 1 + cc;
        if (ct < 0 || ct > 31) continue;
        const int c0 = ct * 64;
        const u16* Kb = &Ks[cc * 4096];
        const u16* Vb = &Vs[cc * 4096];

        // S = (Q/8) K^T, C layout: row(q) = 4*fq+r, col(k) = fr
        f32x4 s[4];
        #pragma unroll
        for (int j = 0; j < 4; ++j) s[j] = (f32x4)0.f;
        #pragma unroll
        for (int j = 0; j < 4; ++j) {
            const int krow = 16 * j + fr;
            #pragma unroll
            for (int ks = 0; ks < 2; ++ks) {
                const int ka = (krow * 64 + fq * 8 + 32 * ks) ^ swz;
                const f16x8 kf = *(const f16x8*)&Kb[ka];
                s[j] = __builtin_amdgcn_mfma_f32_16x16x32_f16(qf[ks], kf, s[j], 0, 0, 0);
            }
        }

        // + time bias (-|dp|) + key padding mask
        float pm[4];
        #pragma unroll
        for (int j = 0; j < 4; ++j)
            pm[j] = (pmask[b * P_SZ + c0 + 16 * j + fr] > 0.f) ? 0.f : -1e9f;
        #pragma unroll
        for (int j = 0; j < 4; ++j)
            #pragma unroll
            for (int r = 0; r < 4; ++r) {
                const int diff = (q0 + 16 * w + 4 * fq + r) - (c0 + 16 * j + fr);
                s[j][r] += pm[j] - fabsf((float)diff);
            }

        // online softmax (row stats across fr-lanes via shfl_xor 1/2/4/8)
        float scale_[4], lloc[4];
        #pragma unroll
        for (int r = 0; r < 4; ++r) {
            float ml = fmaxf(fmaxf(s[0][r], s[1][r]), fmaxf(s[2][r], s[3][r]));
            ml = fmaxf(ml, __shfl_xor(ml, 1));
            ml = fmaxf(ml, __shfl_xor(ml, 2));
            ml = fmaxf(ml, __shfl_xor(ml, 4));
            ml = fmaxf(ml, __shfl_xor(ml, 8));
            const float mnew = fmaxf(m_run[r], ml);
            scale_[r] = __expf(m_run[r] - mnew);
            m_run[r] = mnew;
            lloc[r] = 0.f;
        }
        #pragma unroll
        for (int j = 0; j < 4; ++j)
            #pragma unroll
            for (int r = 0; r < 4; ++r) {
                const float p = __expf(s[j][r] - m_run[r]);
                s[j][r] = p;
                lloc[r] += p;
            }
        #pragma unroll
        for (int r = 0; r < 4; ++r) {
            float ll = lloc[r];
            ll += __shfl_xor(ll, 1);
            ll += __shfl_xor(ll, 2);
            ll += __shfl_xor(ll, 4);
            ll += __shfl_xor(ll, 8);
            l_run[r] = l_run[r] * scale_[r] + ll;
            o[0][r] *= scale_[r]; o[1][r] *= scale_[r];
            o[2][r] *= scale_[r]; o[3][r] *= scale_[r];
        }

        // P -> LDS fp16 (swizzled; rows wave-private, same-wave ordering)
        #pragma unroll
        for (int j = 0; j < 4; ++j)
            #pragma unroll
            for (int r = 0; r < 4; ++r) {
                const int prow = 16 * w + 4 * fq + r;
                const int idx = (prow * 64 + 16 * j + fr) ^ ((prow & 7) << 3);
                Ps[idx] = f2h(s[j][r]);
            }

        // O += P V  (A = P rows fr of this wave's strip; B = Vt rows d)
        const int prow = 16 * w + fr;
        #pragma unroll
        for (int ks = 0; ks < 2; ++ks) {
            const int pa = (prow * 64 + fq * 8 + 32 * ks) ^ swz;
            const f16x8 pf = *(const f16x8*)&Ps[pa];
            #pragma unroll
            for (int jd = 0; jd < 4; ++jd) {
                const int va = ((16 * jd + fr) * 64 + fq * 8 + 32 * ks) ^ swz;
                const f16x8 vf = *(const f16x8*)&Vb[va];
                o[jd] = __builtin_amdgcn_mfma_f32_16x16x32_f16(pf, vf, o[jd], 0, 0, 0);
            }
        }
    }

    // normalize, emit ao fp16 at [B,P,H*Dh] for the O-projection
    #pragma unroll
    for (int r = 0; r < 4; ++r) {
        const float inv = 1.0f / l_run[r];
        const int p = q0 + 16 * w + 4 * fq + r;
        #pragma unroll
        for (int jd = 0; jd < 4; ++jd) {
            const float val = o[jd][r] * inv;
            const size_t idx = ((size_t)(b * P_SZ + p)) * DM_SZ + h * DH_SZ + 16 * jd + fr;
            aoc[idx] = f2h(val);
        }
    }
}

// ---------------------------------------------------------------------------
// O-projection: out = (ao @ Wo^T + bo) * patch_mask, fp16 single term.
// ---------------------------------------------------------------------------
__global__ __launch_bounds__(256, 2)
void o_mfma(const u16* __restrict__ aoc, const u16* __restrict__ Woc,
            const float* __restrict__ bo, const float* __restrict__ pmask,
            float* __restrict__ outp)
{
    __shared__ u16 As[4096], Bs[4096];

    const int bm = blockIdx.x;
    const int n0 = blockIdx.y * 128;
    const int t = threadIdx.x, w = t >> 6, lane = t & 63;
    const int lr = lane >> 2, lk = lane & 3;
    const int wr = w >> 1, wc = w & 1;
    const int fr = lane & 15, fq = lane >> 4;

    const u16* aS = aoc + (size_t)(bm * 128 + w * 32 + lr) * DM_SZ + lk * 8;
    const u16* bS = Woc + (size_t)(n0 + w * 32 + lr) * DM_SZ + lk * 8;
    u16* dA = &As[w * 1024];
    u16* dB = &Bs[w * 1024];

    const int aoff = (wr * 64 + fr) * 32 + fq * 8;
    const int boff = (wc * 64 + fr) * 32 + fq * 8;

    f32x4 acc[4][4];
    #pragma unroll
    for (int i = 0; i < 4; ++i)
        #pragma unroll
        for (int j = 0; j < 4; ++j) acc[i][j] = (f32x4)0.f;

    for (int kt = 0; kt < DM_SZ / 32; ++kt) {
        const int ko_ = kt * 32;
        __syncthreads();
        gload16(aS + ko_, dA); gload16(aS + ko_ + 16 * DM_SZ, dA + 512);
        gload16(bS + ko_, dB); gload16(bS + ko_ + 16 * DM_SZ, dB + 512);
        __syncthreads();

        f16x8 fa[4], fb[4];
        #pragma unroll
        for (int f = 0; f < 4; ++f) {
            fa[f] = *(const f16x8*)&As[aoff + f * 512];
            fb[f] = *(const f16x8*)&Bs[boff + f * 512];
        }
        #pragma unroll
        for (int i = 0; i < 4; ++i)
            #pragma unroll
            for (int j = 0; j < 4; ++j)
                acc[i][j] = __builtin_amdgcn_mfma_f32_16x16x32_f16(fa[i], fb[j], acc[i][j], 0, 0, 0);
    }

    #pragma unroll
    for (int i = 0; i < 4; ++i) {
        const int rbase = bm * 128 + wr * 64 + i * 16 + fq * 4;
        #pragma unroll
        for (int j = 0; j < 4; ++j) {
            const int n  = n0 + wc * 64 + j * 16 + fr;
            const float bb = bo[n];
            #pragma unroll
            for (int r = 0; r < 4; ++r) {
                const int m = rbase + r;
                outp[(size_t)m * DM_SZ + n] = (acc[i][j][r] + bb) * pmask[m];
            }
        }
    }
}

// ===========================================================================
extern "C" void kernel_launch(void* const* d_in, const int* in_sizes, int n_in,
                              void* d_out, int out_size, void* d_ws, size_t ws_size,
                              hipStream_t stream)
{
    const float* x     = (const float*)d_in[0];
    const float* pmask = (const float*)d_in[1];
    const float* Wq    = (const float*)d_in[2];
    const float* bq    = (const float*)d_in[3];
    const float* Wk    = (const float*)d_in[4];
    const float* bk    = (const float*)d_in[5];
    const float* Wv    = (const float*)d_in[6];
    const float* bv    = (const float*)d_in[7];
    const float* Wo    = (const float*)d_in[8];
    const float* bo    = (const float*)d_in[9];

    // ws layout — 75 MiB:
    //  xc        8.4M u16 = 16 MiB   (reused as aoc after qkv_mfma consumes it)
    //  W casts   4 x 1M u16 = 8 MiB
    //  qc,kc,vtc 3 x 8.4M u16 = 48 MiB
    u16* xc  = (u16*)d_ws;
    u16* wqc = xc + (size_t)QKV_ELEMS;
    u16* wkc = wqc + 1048576;
    u16* wvc = wkc + 1048576;
    u16* woc = wvc + 1048576;
    u16* qc  = woc + 1048576;
    u16* kc  = qc + (size_t)QKV_ELEMS;
    u16* vtc = kc + (size_t)QKV_ELEMS;
    u16* aoc = xc;   // x cast dead after qkv_mfma; stream order makes this safe

    cast_inputs<<<dim3(1024), 256, 0, stream>>>(
        (const float4*)x, (const float4*)Wq, (const float4*)Wk,
        (const float4*)Wv, (const float4*)Wo,
        xc, wqc, wkc, wvc, woc);

    qkv_mfma<<<dim3(64, 8, 3), 256, 0, stream>>>(
        xc, wqc, wkc, wvc, bq, bk, bv, qc, kc, vtc);

    attn_mfma<<<dim3(2048), 256, 0, stream>>>(
        qc, kc, vtc, pmask, aoc);

    o_mfma<<<dim3(64, 8), 256, 0, stream>>>(aoc, woc, bo, pmask, (float*)d_out);
}